// Round 9
// baseline (108.582 us; speedup 1.0000x reference)
//
#include <hip/hip_runtime.h>
#include <math.h>

// Problem constants: B=2, S=2048, D=1024, H=16, DQ=64
#define BB 2
#define SS 2048
#define DD 1024
#define HH 16
#define DQK 64
#define NROWS (BB * SS)
#define NE ((size_t)BB * SS * DD)   // 4,194,304

using short8 = __attribute__((ext_vector_type(8))) short;
using f32x4  = __attribute__((ext_vector_type(4))) float;

__device__ __forceinline__ ushort f2bf(float f) {
  union { float f; unsigned u; } c; c.f = f;
  return (ushort)((c.u + 0x7fffu + ((c.u >> 16) & 1u)) >> 16);
}

__device__ __forceinline__ unsigned cvt_pk_bf16(float lo, float hi) {
  unsigned r;
  asm("v_cvt_pk_bf16_f32 %0, %1, %2" : "=v"(r) : "v"(lo), "v"(hi));
  return r;
}

__device__ __forceinline__ f32x4 mfma16(short8 a, short8 b, f32x4 c) {
  return __builtin_amdgcn_mfma_f32_16x16x32_bf16(a, b, c, 0, 0, 0);
}

typedef __attribute__((address_space(1))) const unsigned gas_u32;
typedef __attribute__((address_space(3))) unsigned las_u32;
__device__ __forceinline__ void gload_lds16(const void* g, void* l) {
  __builtin_amdgcn_global_load_lds((gas_u32*)g, (las_u32*)l, 16, 0, 0);
}

// ---------------------------------------------------------------------------
// Fused prepass: blocks [0,4096) do LayerNorm->bf16 (one row each);
// blocks [4096,5120) transpose+cast the 4 weight matrices to Wt[N][K] bf16.
// ---------------------------------------------------------------------------
__global__ __launch_bounds__(256) void prep(const float* __restrict__ x,
                                            const float* __restrict__ g,
                                            const float* __restrict__ bta,
                                            ushort* __restrict__ xn,
                                            const float* __restrict__ Wq,
                                            const float* __restrict__ Wk,
                                            const float* __restrict__ Wv,
                                            const float* __restrict__ Wo,
                                            ushort* __restrict__ wt) {
  __shared__ float tile[64][65];
  const int t = threadIdx.x;
  if (blockIdx.x < NROWS) {
    const int row = blockIdx.x;
    float4 v = ((const float4*)(x + (size_t)row * DD))[t];
    float s  = v.x + v.y + v.z + v.w;
    float ss = v.x * v.x + v.y * v.y + v.z * v.z + v.w * v.w;
#pragma unroll
    for (int off = 32; off > 0; off >>= 1) {
      s  += __shfl_xor(s, off);
      ss += __shfl_xor(ss, off);
    }
    const int wid = t >> 6, lane = t & 63;
    if (lane == 0) { tile[0][wid] = s; tile[0][4 + wid] = ss; }
    __syncthreads();
    const float stot  = tile[0][0] + tile[0][1] + tile[0][2] + tile[0][3];
    const float sstot = tile[0][4] + tile[0][5] + tile[0][6] + tile[0][7];
    const float mu  = stot * (1.0f / DD);
    const float var = sstot * (1.0f / DD) - mu * mu;
    const float inv = rsqrtf(var + 1e-5f);
    const float4 g4 = ((const float4*)g)[t];
    const float4 b4 = ((const float4*)bta)[t];
    ushort4 o;
    o.x = f2bf((v.x - mu) * inv * g4.x + b4.x);
    o.y = f2bf((v.y - mu) * inv * g4.y + b4.y);
    o.z = f2bf((v.z - mu) * inv * g4.z + b4.z);
    o.w = f2bf((v.w - mu) * inv * g4.w + b4.w);
    ((ushort4*)(xn + (size_t)row * DD))[t] = o;
  } else {
    const int wb = blockIdx.x - NROWS;        // 0..1023
    const int z = wb >> 8;                    // matrix id
    const int k0 = (wb & 15) * 64, n0 = ((wb >> 4) & 15) * 64;
    const float* W = (z == 0) ? Wq : (z == 1) ? Wk : (z == 2) ? Wv : Wo;
    ushort* dst = wt + (size_t)z * DD * DD;
    const int tr = t >> 4, tc = (t & 15) * 4;
#pragma unroll
    for (int rr = 0; rr < 64; rr += 16) {
      float4 v = *(const float4*)(W + (size_t)(k0 + rr + tr) * DD + n0 + tc);
      tile[rr + tr][tc + 0] = v.x;
      tile[rr + tr][tc + 1] = v.y;
      tile[rr + tr][tc + 2] = v.z;
      tile[rr + tr][tc + 3] = v.w;
    }
    __syncthreads();
#pragma unroll
    for (int rr = 0; rr < 64; rr += 16) {
      const int n = rr + tr;
      ushort4 o;
      o.x = f2bf(tile[tc + 0][n]);
      o.y = f2bf(tile[tc + 1][n]);
      o.z = f2bf(tile[tc + 2][n]);
      o.w = f2bf(tile[tc + 3][n]);
      *(ushort4*)(dst + (size_t)(n0 + n) * DD + k0 + tc) = o;
    }
  }
}

// ---------------------------------------------------------------------------
// 128x128 GEMM core. 4 waves, BK=32, triple-buffered global_load_lds with
// counted vmcnt(4) + raw s_barrier. Read-side XOR (r16>>1)&3 (row bits 1-2).
// ---------------------------------------------------------------------------
#define GEMM_CORE(Ag, Bg)                                                     \
  f32x4 acc[4][4];                                                            \
  _Pragma("unroll")                                                           \
  for (int m = 0; m < 4; ++m)                                                 \
    _Pragma("unroll")                                                         \
    for (int n = 0; n < 4; ++n) acc[m][n] = (f32x4){0.f, 0.f, 0.f, 0.f};     \
  const int cs = ((t & 3) * 16) ^ (((t >> 3) & 3) * 16);                      \
  const int fsw = ((r16 >> 1) & 3) * 16;                                      \
  {                                                                           \
    GSTAGE(Ag, Bg, 0, 0);                                                     \
    GSTAGE(Ag, Bg, 1, 32);                                                    \
    int cb = 0;                                                               \
    for (int k0 = 0; k0 < DD; k0 += 32) {                                     \
      __builtin_amdgcn_sched_barrier(0);                                      \
      if (k0 + 32 < DD) {                                                     \
        asm volatile("s_waitcnt vmcnt(4)" ::: "memory");                      \
      } else {                                                                \
        asm volatile("s_waitcnt vmcnt(0)" ::: "memory");                      \
      }                                                                       \
      __builtin_amdgcn_s_barrier();                                           \
      __builtin_amdgcn_sched_barrier(0);                                      \
      if (k0 + 64 < DD) {                                                     \
        int nb = cb + 2; if (nb >= 3) nb -= 3;                                \
        GSTAGE(Ag, Bg, nb, k0 + 64);                                          \
      }                                                                       \
      const char* Ac = (const char*)&As[cb][0][0];                            \
      const char* Bc = (const char*)&Bs[cb][0][0];                            \
      short8 af[4], bf[4];                                                    \
      _Pragma("unroll")                                                       \
      for (int m = 0; m < 4; ++m)                                             \
        af[m] = *(const short8*)(Ac + (wr * 64 + m * 16 + r16) * 64 +         \
                                 ((g * 16) ^ fsw));                           \
      _Pragma("unroll")                                                       \
      for (int n = 0; n < 4; ++n)                                             \
        bf[n] = *(const short8*)(Bc + (wc * 64 + n * 16 + r16) * 64 +         \
                                 ((g * 16) ^ fsw));                           \
      _Pragma("unroll")                                                       \
      for (int m = 0; m < 4; ++m)                                             \
        _Pragma("unroll")                                                     \
        for (int n = 0; n < 4; ++n) acc[m][n] = mfma16(af[m], bf[n], acc[m][n]); \
      cb = (cb + 1 == 3) ? 0 : cb + 1;                                        \
    }                                                                         \
  }

#define GSTAGE(Ag, Bg, buf, k0)                                               \
  {                                                                           \
    _Pragma("unroll")                                                         \
    for (int i = 0; i < 2; ++i) {                                             \
      gload_lds16(Ag + (size_t)(row0 + i * 64 + (t >> 2)) * (DD * 2) +        \
                      (k0) * 2 + cs,                                          \
                  (char*)&As[buf][0][0] + i * 4096 + t * 16);                 \
      gload_lds16(Bg + (size_t)(col0 + i * 64 + (t >> 2)) * (DD * 2) +        \
                      (k0) * 2 + cs,                                          \
                  (char*)&Bs[buf][0][0] + i * 4096 + t * 16);                 \
    }                                                                         \
  }

// 128x64 GEMM core (for gemm_o): 512 blocks -> 2 blocks/CU, 2 waves/SIMD.
// Waves 2x2 over 128x64; per-wave 64x32 = acc[4][2]; 3 loads/stage/thread.
#define GEMM_CORE_O(Ag, Bg)                                                   \
  f32x4 acc[4][2];                                                            \
  _Pragma("unroll")                                                           \
  for (int m = 0; m < 4; ++m)                                                 \
    _Pragma("unroll")                                                         \
    for (int n = 0; n < 2; ++n) acc[m][n] = (f32x4){0.f, 0.f, 0.f, 0.f};     \
  const int cs = ((t & 3) * 16) ^ (((t >> 3) & 3) * 16);                      \
  const int fsw = ((r16 >> 1) & 3) * 16;                                      \
  {                                                                           \
    GSTAGE_O(Ag, Bg, 0, 0);                                                   \
    GSTAGE_O(Ag, Bg, 1, 32);                                                  \
    int cb = 0;                                                               \
    for (int k0 = 0; k0 < DD; k0 += 32) {                                     \
      __builtin_amdgcn_sched_barrier(0);                                      \
      if (k0 + 32 < DD) {                                                     \
        asm volatile("s_waitcnt vmcnt(3)" ::: "memory");                      \
      } else {                                                                \
        asm volatile("s_waitcnt vmcnt(0)" ::: "memory");                      \
      }                                                                       \
      __builtin_amdgcn_s_barrier();                                           \
      __builtin_amdgcn_sched_barrier(0);                                      \
      if (k0 + 64 < DD) {                                                     \
        int nb = cb + 2; if (nb >= 3) nb -= 3;                                \
        GSTAGE_O(Ag, Bg, nb, k0 + 64);                                        \
      }                                                                       \
      const char* Ac = (const char*)&As[cb][0][0];                            \
      const char* Bc = (const char*)&Bs[cb][0][0];                            \
      short8 af[4], bf[2];                                                    \
      _Pragma("unroll")                                                       \
      for (int m = 0; m < 4; ++m)                                             \
        af[m] = *(const short8*)(Ac + (wr * 64 + m * 16 + r16) * 64 +         \
                                 ((g * 16) ^ fsw));                           \
      _Pragma("unroll")                                                       \
      for (int n = 0; n < 2; ++n)                                             \
        bf[n] = *(const short8*)(Bc + (wc * 32 + n * 16 + r16) * 64 +         \
                                 ((g * 16) ^ fsw));                           \
      _Pragma("unroll")                                                       \
      for (int m = 0; m < 4; ++m)                                             \
        _Pragma("unroll")                                                     \
        for (int n = 0; n < 2; ++n) acc[m][n] = mfma16(af[m], bf[n], acc[m][n]); \
      cb = (cb + 1 == 3) ? 0 : cb + 1;                                        \
    }                                                                         \
  }

#define GSTAGE_O(Ag, Bg, buf, k0)                                             \
  {                                                                           \
    _Pragma("unroll")                                                         \
    for (int i = 0; i < 2; ++i)                                               \
      gload_lds16(Ag + (size_t)(row0 + i * 64 + (t >> 2)) * (DD * 2) +        \
                      (k0) * 2 + cs,                                          \
                  (char*)&As[buf][0][0] + i * 4096 + t * 16);                 \
    gload_lds16(Bg + (size_t)(col0 + (t >> 2)) * (DD * 2) + (k0) * 2 + cs,    \
                (char*)&Bs[buf][0][0] + t * 16);                              \
  }

// Fused QKV projection. Q output is PRE-SCALED by 1/sqrt(64)*log2(e).
__global__ __launch_bounds__(256) void gemm_qkv(
    const ushort* __restrict__ A, const ushort* __restrict__ wt,
    const float* __restrict__ bq, const float* __restrict__ bk,
    const float* __restrict__ bv, ushort* __restrict__ qb,
    ushort* __restrict__ kb, ushort* __restrict__ vt) {
  __shared__ ushort As[3][128][32];
  __shared__ ushort Bs[3][128][32];
  const int t = threadIdx.x;
  const int lane = t & 63;
  const int w = t >> 6, wr = w >> 1, wc = w & 1;
  const int r16 = lane & 15, g = lane >> 4;
  const int row0 = blockIdx.x * 128;
  const int mat = blockIdx.y >> 3;
  const int col0 = (blockIdx.y & 7) * 128;
  const char* Ag = (const char*)A;
  const char* Bg = (const char*)(wt + (size_t)mat * DD * DD);
  const float* bias = (mat == 0) ? bq : (mat == 1) ? bk : bv;
  const float scl = (mat == 0) ? 0.125f * 1.44269504f : 1.0f;

  GEMM_CORE(Ag, Bg)

#pragma unroll
  for (int n = 0; n < 4; ++n) {
    const int c = col0 + wc * 64 + n * 16 + r16;
    const float bc = bias[c];
#pragma unroll
    for (int m = 0; m < 4; ++m) {
      const int rbase = row0 + wr * 64 + m * 16 + g * 4;
      if (mat < 2) {
        ushort* outb = (mat == 0) ? qb : kb;
#pragma unroll
        for (int e = 0; e < 4; ++e)
          outb[(size_t)(rbase + e) * DD + c] = f2bf((acc[m][n][e] + bc) * scl);
      } else {
        uint2 st;
        st.x = cvt_pk_bf16(acc[m][n][0] + bc, acc[m][n][1] + bc);
        st.y = cvt_pk_bf16(acc[m][n][2] + bc, acc[m][n][3] + bc);
        const size_t vrow = (size_t)((rbase >> 11) * HH + (c >> 6)) * DQK + (c & 63);
        *(uint2*)(vt + vrow * SS + (rbase & 2047)) = st;
      }
    }
  }
}

// Output projection: att @ Wo + bo + x -> fp32 out. 128x64 tiles, 512 blocks.
__global__ __launch_bounds__(256) void gemm_o(
    const ushort* __restrict__ A, const ushort* __restrict__ Bt,
    const float* __restrict__ bias, const float* __restrict__ resid,
    float* __restrict__ outf) {
  __shared__ ushort As[3][128][32];
  __shared__ ushort Bs[3][64][32];
  const int t = threadIdx.x;
  const int lane = t & 63;
  const int w = t >> 6, wr = w >> 1, wc = w & 1;
  const int r16 = lane & 15, g = lane >> 4;
  const int row0 = blockIdx.x * 128;
  const int col0 = blockIdx.y * 64;
  const char* Ag = (const char*)A;
  const char* Bg = (const char*)Bt;

  GEMM_CORE_O(Ag, Bg)

#pragma unroll
  for (int n = 0; n < 2; ++n) {
    const int c = col0 + wc * 32 + n * 16 + r16;
    const float bc = bias[c];
#pragma unroll
    for (int m = 0; m < 4; ++m) {
      const int rbase = row0 + wr * 64 + m * 16 + g * 4;
#pragma unroll
      for (int e = 0; e < 4; ++e) {
        const size_t idx = (size_t)(rbase + e) * DD + c;
        outf[idx] = acc[m][n][e] + bc + resid[idx];
      }
    }
  }
}

// ---------------------------------------------------------------------------
// MFMA flash attention (causal). 512 blocks, each processes q-block PAIR
// (31-p, p) of one (b,h) as ONE virtual 33-tile key stream (uniform work,
// zero tail; 2 blocks/CU). Triple-buffered K/V with counted waits:
// STAGE issues K,K,V,V; per tile vmcnt(6) -> barrier -> QK -> softmax ->
// vmcnt(8) -> barrier -> PV. Key relabeling keeps P in registers.
// ---------------------------------------------------------------------------
__global__ __launch_bounds__(256) void attn_mfma(const ushort* __restrict__ Q,
                                                 const ushort* __restrict__ K,
                                                 const ushort* __restrict__ Vt,
                                                 ushort* __restrict__ O) {
  __shared__ ushort Ks[3][64][64];  // [buf][key][d]  128B rows, swizzled
  __shared__ ushort Vs[3][64][64];  // [buf][dq][key] 128B rows, swizzled

  const int t = threadIdx.x, lane = t & 63, ww = t >> 6;
  const int r16 = lane & 15, g = lane >> 4;

  const int bid = blockIdx.x;                    // 512 blocks
  const int xcd = bid & 7;
  const int bh = xcd * 4 + ((bid >> 3) & 3);     // 4 heads per XCD
  const int p = bid >> 5;                        // 0..15
  const int nt1 = 32 - p;                        // seg1: qb = 31-p
  const int nt2 = p + 1;                         // seg2: qb = p
  const int b = bh >> 4, h = bh & 15;
  const size_t tokbase = (size_t)b * SS;
  const size_t hoff = (size_t)h * DQK;

  const int srow = t >> 3;                       // 0..31
  const int scol = (t & 7) * 16;                 // 0..112
  const char* Kb = (const char*)(K + tokbase * DD + hoff);
  const char* Vb = (const char*)(Vt + (size_t)bh * DQK * SS);
  const int sw = ((r16 & 3) | ((r16 >> 1) & 4)) << 4;  // V-read swz, bits {0,1,3}
  const int rlo = (r16 & 3) + ((r16 >> 2) << 3);       // K-row permutation base

#define STAGE(buf, j0)                                                        \
  {                                                                           \
    _Pragma("unroll")                                                         \
    for (int i = 0; i < 2; ++i) {                                             \
      const int R = i * 32 + srow;                                            \
      const int Cs = scol ^ (((R & 3) | ((R >> 1) & 4)) << 4);                \
      gload_lds16(Kb + ((size_t)((j0) + R) * DD) * 2 + Cs,                    \
                  (char*)&Ks[buf][0][0] + i * 4096 + ww * 1024);              \
    }                                                                         \
    _Pragma("unroll")                                                         \
    for (int i = 0; i < 2; ++i) {                                             \
      const int R = i * 32 + srow;                                            \
      const int Cs = scol ^ (((R & 3) | ((R >> 1) & 4)) << 4);                \
      gload_lds16(Vb + ((size_t)R * SS + (j0)) * 2 + Cs,                      \
                  (char*)&Vs[buf][0][0] + i * 4096 + ww * 1024);              \
    }                                                                         \
  }

  // Preload Q fragments for both segments (pre-scaled in exp2 domain).
  int q0 = (31 - p) * 64 + ww * 16;
  const int q02 = p * 64 + ww * 16;
  short8 qc0, qc1, q2f0, q2f1;
  qc0 = *(const short8*)(Q + (tokbase + q0 + r16) * DD + hoff + 0 * 32 + g * 8);
  qc1 = *(const short8*)(Q + (tokbase + q0 + r16) * DD + hoff + 1 * 32 + g * 8);
  q2f0 = *(const short8*)(Q + (tokbase + q02 + r16) * DD + hoff + 0 * 32 + g * 8);
  q2f1 = *(const short8*)(Q + (tokbase + q02 + r16) * DD + hoff + 1 * 32 + g * 8);

  f32x4 o[4];
#pragma unroll
  for (int dt = 0; dt < 4; ++dt) o[dt] = (f32x4){0.f, 0.f, 0.f, 0.f};
  float rm = -INFINITY, rl = 0.f;                // rl is a per-lane PARTIAL

  STAGE(0, 0);
  STAGE(1, 64);                                  // nt1 >= 17, always valid
  int cb = 0;
#pragma unroll 1
  for (int vt = 0; vt < 33; ++vt) {
    if (vt == nt1) {                             // segment switch (uniform)
      float rls = rl;
      rls += __shfl_xor(rls, 16);
      rls += __shfl_xor(rls, 32);
      const float inv = 1.0f / rls;
#pragma unroll
      for (int dt = 0; dt < 4; ++dt) {
        uint2 st;
        st.x = cvt_pk_bf16(o[dt][0] * inv, o[dt][1] * inv);
        st.y = cvt_pk_bf16(o[dt][2] * inv, o[dt][3] * inv);
        *(uint2*)(O + (tokbase + q0 + r16) * DD + hoff + dt * 16 + g * 4) = st;
        o[dt] = (f32x4){0.f, 0.f, 0.f, 0.f};
      }
      rm = -INFINITY; rl = 0.f;
      q0 = q02; qc0 = q2f0; qc1 = q2f1;
    }

    __builtin_amdgcn_sched_barrier(0);
    asm volatile("s_waitcnt vmcnt(6)" ::: "memory");  // this tile's K ready
    __builtin_amdgcn_s_barrier();
    __builtin_amdgcn_sched_barrier(0);

    {                                            // prefetch virtual tile vt+2
      const int w2 = vt + 2;
      int jj = (w2 < nt1) ? w2 : (w2 - nt1);
      if (w2 >= nt1 && jj >= nt2) jj = 0;        // dummy (harmless reload)
      int nb = cb + 2; if (nb >= 3) nb -= 3;
      STAGE(nb, jj * 64);
    }

    const char* Kc = (const char*)&Ks[cb][0][0];
    const char* Vc = (const char*)&Vs[cb][0][0];

    // --- QK^T with permuted K-rows: lane (r16,g) of s4[t2] holds physical
    // keys {(t2&1)*4 + r + g*8 + (t2>>1)*32}, q = r16 ---
    f32x4 s4[4];
    __builtin_amdgcn_s_setprio(1);
#pragma unroll
    for (int t2 = 0; t2 < 4; ++t2) {
      const int kk = rlo + (t2 & 1) * 4 + (t2 >> 1) * 32;
      const int sk = ((kk & 3) | ((kk >> 1) & 4)) << 4;
      const int rb = kk * 128;
      const short8 k0 = *(const short8*)(Kc + rb + ((g * 16) ^ sk));
      const short8 k1 = *(const short8*)(Kc + rb + ((64 + g * 16) ^ sk));
      f32x4 s = mfma16(k0, qc0, (f32x4){0.f, 0.f, 0.f, 0.f});
      s4[t2] = mfma16(k1, qc1, s);
    }
    __builtin_amdgcn_s_setprio(0);

    const bool lastseg = (vt == nt1 - 1) || (vt == 32);
    if (lastseg) {                               // mask diagonal tile only
      const int tloc = (vt >= nt1) ? (vt - nt1) : vt;
      const int thrl = q0 + r16 - g * 8 - tloc * 64;
#pragma unroll
      for (int t2 = 0; t2 < 4; ++t2) {
        const int bb = (t2 & 1) * 4 + (t2 >> 1) * 32;
#pragma unroll
        for (int r = 0; r < 4; ++r)
          s4[t2][r] = (bb + r <= thrl) ? s4[t2][r] : -INFINITY;
      }
    }

    // --- in-lane max over this lane's 16 keys ---
    float mx = fmaxf(
        fmaxf(fmaxf(fmaxf(s4[0][0], s4[0][1]), fmaxf(s4[0][2], s4[0][3])),
              fmaxf(fmaxf(s4[1][0], s4[1][1]), fmaxf(s4[1][2], s4[1][3]))),
        fmaxf(fmaxf(fmaxf(s4[2][0], s4[2][1]), fmaxf(s4[2][2], s4[2][3])),
              fmaxf(fmaxf(s4[3][0], s4[3][1]), fmaxf(s4[3][2], s4[3][3]))));

    // --- defer-max: rescale only when some lane's max grew past rm+8 ---
    if (!__all(mx - rm <= 8.f)) {
      float mf = fmaxf(mx, __shfl_xor(mx, 16));
      mf = fmaxf(mf, __shfl_xor(mf, 32));        // column max over 64 keys
      const float mn = fmaxf(rm, mf);
      const float sc = __builtin_amdgcn_exp2f(rm - mn);
      rl *= sc;
#pragma unroll
      for (int dt = 0; dt < 4; ++dt) o[dt] *= sc;
      rm = mn;
    }

    // --- P = exp2(S - rm), packed IN-LANE directly to PV B-frags ---
    union { unsigned u[4]; short8 s; } pbu[2];
#pragma unroll
    for (int t2 = 0; t2 < 4; ++t2) {
      const float p0 = __builtin_amdgcn_exp2f(s4[t2][0] - rm);
      const float p1 = __builtin_amdgcn_exp2f(s4[t2][1] - rm);
      const float p2 = __builtin_amdgcn_exp2f(s4[t2][2] - rm);
      const float p3 = __builtin_amdgcn_exp2f(s4[t2][3] - rm);
      rl += (p0 + p1) + (p2 + p3);
      pbu[t2 >> 1].u[(t2 & 1) * 2 + 0] = cvt_pk_bf16(p0, p1);
      pbu[t2 >> 1].u[(t2 & 1) * 2 + 1] = cvt_pk_bf16(p2, p3);
    }

    __builtin_amdgcn_sched_barrier(0);
    asm volatile("s_waitcnt vmcnt(8)" ::: "memory");  // this tile's V ready
    __builtin_amdgcn_s_barrier();
    __builtin_amdgcn_sched_barrier(0);

    // --- PV: O[dq][q] ---
    __builtin_amdgcn_s_setprio(1);
#pragma unroll
    for (int kc = 0; kc < 2; ++kc) {
#pragma unroll
      for (int dt = 0; dt < 4; ++dt) {
        const short8 vf = *(const short8*)(Vc + (dt * 16 + r16) * 128 +
                                           ((kc * 64 + g * 16) ^ sw));
        o[dt] = mfma16(vf, pbu[kc].s, o[dt]);
      }
    }
    __builtin_amdgcn_s_setprio(0);
    cb = (cb + 1 == 3) ? 0 : cb + 1;
  }
#undef STAGE

  // --- epilogue segment 2 ---
  rl += __shfl_xor(rl, 16);
  rl += __shfl_xor(rl, 32);
  const float inv = 1.0f / rl;
#pragma unroll
  for (int dt = 0; dt < 4; ++dt) {
    uint2 st;
    st.x = cvt_pk_bf16(o[dt][0] * inv, o[dt][1] * inv);
    st.y = cvt_pk_bf16(o[dt][2] * inv, o[dt][3] * inv);
    *(uint2*)(O + (tokbase + q0 + r16) * DD + hoff + dt * 16 + g * 4) = st;
  }
}

// ---------------------------------------------------------------------------
// Launch: prep (LN + wtrans fused) -> fused QKV GEMM -> attn -> O-GEMM.
// ws: xn 8MB | q 8MB | k 8MB | vt 8MB | att 8MB | wt 16MB  (56MB)
// ---------------------------------------------------------------------------
extern "C" void kernel_launch(void* const* d_in, const int* in_sizes, int n_in,
                              void* d_out, int out_size, void* d_ws, size_t ws_size,
                              hipStream_t stream) {
  const float* x    = (const float*)d_in[0];
  const float* ln_g = (const float*)d_in[1];
  const float* ln_b = (const float*)d_in[2];
  const float* Wq   = (const float*)d_in[3];
  const float* bq   = (const float*)d_in[4];
  const float* Wk   = (const float*)d_in[5];
  const float* bk   = (const float*)d_in[6];
  const float* Wv   = (const float*)d_in[7];
  const float* bv   = (const float*)d_in[8];
  const float* Wo   = (const float*)d_in[9];
  const float* bo   = (const float*)d_in[10];
  float* out = (float*)d_out;

  ushort* ws  = (ushort*)d_ws;
  ushort* xn  = ws;
  ushort* qb  = xn + NE;
  ushort* kb  = qb + NE;
  ushort* vt  = kb + NE;
  ushort* ab  = vt + NE;
  ushort* wt  = ab + NE;               // 4 x [1024][1024] bf16
  ushort* wot = wt + (size_t)3 * DD * DD;

  prep<<<NROWS + 1024, 256, 0, stream>>>(x, ln_g, ln_b, xn, Wq, Wk, Wv, Wo, wt);

  gemm_qkv<<<dim3(NROWS / 128, 24), 256, 0, stream>>>(xn, wt, bq, bk, bv,
                                                      qb, kb, vt);

  attn_mfma<<<BB * HH * (SS / 128), 256, 0, stream>>>(qb, kb, vt, ab);

  gemm_o<<<dim3(NROWS / 128, DD / 64), 256, 0, stream>>>(ab, wot, bo, x, out);
}

// Round 10
// 103.634 us; speedup vs baseline: 1.0477x; 1.0477x over previous
//
#include <hip/hip_runtime.h>
#include <math.h>

// Problem constants: B=2, S=2048, D=1024, H=16, DQ=64
#define BB 2
#define SS 2048
#define DD 1024
#define HH 16
#define DQK 64
#define NROWS (BB * SS)
#define NE ((size_t)BB * SS * DD)   // 4,194,304

using short8 = __attribute__((ext_vector_type(8))) short;
using f32x4  = __attribute__((ext_vector_type(4))) float;

__device__ __forceinline__ ushort f2bf(float f) {
  union { float f; unsigned u; } c; c.f = f;
  return (ushort)((c.u + 0x7fffu + ((c.u >> 16) & 1u)) >> 16);
}

__device__ __forceinline__ unsigned cvt_pk_bf16(float lo, float hi) {
  unsigned r;
  asm("v_cvt_pk_bf16_f32 %0, %1, %2" : "=v"(r) : "v"(lo), "v"(hi));
  return r;
}

__device__ __forceinline__ f32x4 mfma16(short8 a, short8 b, f32x4 c) {
  return __builtin_amdgcn_mfma_f32_16x16x32_bf16(a, b, c, 0, 0, 0);
}

typedef __attribute__((address_space(1))) const unsigned gas_u32;
typedef __attribute__((address_space(3))) unsigned las_u32;
__device__ __forceinline__ void gload_lds16(const void* g, void* l) {
  __builtin_amdgcn_global_load_lds((gas_u32*)g, (las_u32*)l, 16, 0, 0);
}

// ---------------------------------------------------------------------------
// Fused prepass: blocks [0,4096) do LayerNorm->bf16 (one row each);
// blocks [4096,5120) transpose+cast the 4 weight matrices to Wt[N][K] bf16.
// ---------------------------------------------------------------------------
__global__ __launch_bounds__(256) void prep(const float* __restrict__ x,
                                            const float* __restrict__ g,
                                            const float* __restrict__ bta,
                                            ushort* __restrict__ xn,
                                            const float* __restrict__ Wq,
                                            const float* __restrict__ Wk,
                                            const float* __restrict__ Wv,
                                            const float* __restrict__ Wo,
                                            ushort* __restrict__ wt) {
  __shared__ float tile[64][65];
  const int t = threadIdx.x;
  if (blockIdx.x < NROWS) {
    const int row = blockIdx.x;
    float4 v = ((const float4*)(x + (size_t)row * DD))[t];
    float s  = v.x + v.y + v.z + v.w;
    float ss = v.x * v.x + v.y * v.y + v.z * v.z + v.w * v.w;
#pragma unroll
    for (int off = 32; off > 0; off >>= 1) {
      s  += __shfl_xor(s, off);
      ss += __shfl_xor(ss, off);
    }
    const int wid = t >> 6, lane = t & 63;
    if (lane == 0) { tile[0][wid] = s; tile[0][4 + wid] = ss; }
    __syncthreads();
    const float stot  = tile[0][0] + tile[0][1] + tile[0][2] + tile[0][3];
    const float sstot = tile[0][4] + tile[0][5] + tile[0][6] + tile[0][7];
    const float mu  = stot * (1.0f / DD);
    const float var = sstot * (1.0f / DD) - mu * mu;
    const float inv = rsqrtf(var + 1e-5f);
    const float4 g4 = ((const float4*)g)[t];
    const float4 b4 = ((const float4*)bta)[t];
    ushort4 o;
    o.x = f2bf((v.x - mu) * inv * g4.x + b4.x);
    o.y = f2bf((v.y - mu) * inv * g4.y + b4.y);
    o.z = f2bf((v.z - mu) * inv * g4.z + b4.z);
    o.w = f2bf((v.w - mu) * inv * g4.w + b4.w);
    ((ushort4*)(xn + (size_t)row * DD))[t] = o;
  } else {
    const int wb = blockIdx.x - NROWS;        // 0..1023
    const int z = wb >> 8;                    // matrix id
    const int k0 = (wb & 15) * 64, n0 = ((wb >> 4) & 15) * 64;
    const float* W = (z == 0) ? Wq : (z == 1) ? Wk : (z == 2) ? Wv : Wo;
    ushort* dst = wt + (size_t)z * DD * DD;
    const int tr = t >> 4, tc = (t & 15) * 4;
#pragma unroll
    for (int rr = 0; rr < 64; rr += 16) {
      float4 v = *(const float4*)(W + (size_t)(k0 + rr + tr) * DD + n0 + tc);
      tile[rr + tr][tc + 0] = v.x;
      tile[rr + tr][tc + 1] = v.y;
      tile[rr + tr][tc + 2] = v.z;
      tile[rr + tr][tc + 3] = v.w;
    }
    __syncthreads();
#pragma unroll
    for (int rr = 0; rr < 64; rr += 16) {
      const int n = rr + tr;
      ushort4 o;
      o.x = f2bf(tile[tc + 0][n]);
      o.y = f2bf(tile[tc + 1][n]);
      o.z = f2bf(tile[tc + 2][n]);
      o.w = f2bf(tile[tc + 3][n]);
      *(ushort4*)(dst + (size_t)(n0 + n) * DD + k0 + tc) = o;
    }
  }
}

// ---------------------------------------------------------------------------
// 128x128 GEMM core. 4 waves, BK=32, triple-buffered global_load_lds with
// counted vmcnt(4) + raw s_barrier. Read-side XOR (r16>>1)&3 (row bits 1-2).
// ---------------------------------------------------------------------------
#define GEMM_CORE(Ag, Bg)                                                     \
  f32x4 acc[4][4];                                                            \
  _Pragma("unroll")                                                           \
  for (int m = 0; m < 4; ++m)                                                 \
    _Pragma("unroll")                                                         \
    for (int n = 0; n < 4; ++n) acc[m][n] = (f32x4){0.f, 0.f, 0.f, 0.f};     \
  const int cs = ((t & 3) * 16) ^ (((t >> 3) & 3) * 16);                      \
  const int fsw = ((r16 >> 1) & 3) * 16;                                      \
  {                                                                           \
    GSTAGE(Ag, Bg, 0, 0);                                                     \
    GSTAGE(Ag, Bg, 1, 32);                                                    \
    int cb = 0;                                                               \
    for (int k0 = 0; k0 < DD; k0 += 32) {                                     \
      __builtin_amdgcn_sched_barrier(0);                                      \
      if (k0 + 32 < DD) {                                                     \
        asm volatile("s_waitcnt vmcnt(4)" ::: "memory");                      \
      } else {                                                                \
        asm volatile("s_waitcnt vmcnt(0)" ::: "memory");                      \
      }                                                                       \
      __builtin_amdgcn_s_barrier();                                           \
      __builtin_amdgcn_sched_barrier(0);                                      \
      if (k0 + 64 < DD) {                                                     \
        int nb = cb + 2; if (nb >= 3) nb -= 3;                                \
        GSTAGE(Ag, Bg, nb, k0 + 64);                                          \
      }                                                                       \
      const char* Ac = (const char*)&As[cb][0][0];                            \
      const char* Bc = (const char*)&Bs[cb][0][0];                            \
      short8 af[4], bf[4];                                                    \
      _Pragma("unroll")                                                       \
      for (int m = 0; m < 4; ++m)                                             \
        af[m] = *(const short8*)(Ac + (wr * 64 + m * 16 + r16) * 64 +         \
                                 ((g * 16) ^ fsw));                           \
      _Pragma("unroll")                                                       \
      for (int n = 0; n < 4; ++n)                                             \
        bf[n] = *(const short8*)(Bc + (wc * 64 + n * 16 + r16) * 64 +         \
                                 ((g * 16) ^ fsw));                           \
      _Pragma("unroll")                                                       \
      for (int m = 0; m < 4; ++m)                                             \
        _Pragma("unroll")                                                     \
        for (int n = 0; n < 4; ++n) acc[m][n] = mfma16(af[m], bf[n], acc[m][n]); \
      cb = (cb + 1 == 3) ? 0 : cb + 1;                                        \
    }                                                                         \
  }

#define GSTAGE(Ag, Bg, buf, k0)                                               \
  {                                                                           \
    _Pragma("unroll")                                                         \
    for (int i = 0; i < 2; ++i) {                                             \
      gload_lds16(Ag + (size_t)(row0 + i * 64 + (t >> 2)) * (DD * 2) +        \
                      (k0) * 2 + cs,                                          \
                  (char*)&As[buf][0][0] + i * 4096 + t * 16);                 \
      gload_lds16(Bg + (size_t)(col0 + i * 64 + (t >> 2)) * (DD * 2) +        \
                      (k0) * 2 + cs,                                          \
                  (char*)&Bs[buf][0][0] + i * 4096 + t * 16);                 \
    }                                                                         \
  }

// 128x64 GEMM core (for gemm_o): 512 blocks -> 2 blocks/CU, 2 waves/SIMD.
#define GEMM_CORE_O(Ag, Bg)                                                   \
  f32x4 acc[4][2];                                                            \
  _Pragma("unroll")                                                           \
  for (int m = 0; m < 4; ++m)                                                 \
    _Pragma("unroll")                                                         \
    for (int n = 0; n < 2; ++n) acc[m][n] = (f32x4){0.f, 0.f, 0.f, 0.f};     \
  const int cs = ((t & 3) * 16) ^ (((t >> 3) & 3) * 16);                      \
  const int fsw = ((r16 >> 1) & 3) * 16;                                      \
  {                                                                           \
    GSTAGE_O(Ag, Bg, 0, 0);                                                   \
    GSTAGE_O(Ag, Bg, 1, 32);                                                  \
    int cb = 0;                                                               \
    for (int k0 = 0; k0 < DD; k0 += 32) {                                     \
      __builtin_amdgcn_sched_barrier(0);                                      \
      if (k0 + 32 < DD) {                                                     \
        asm volatile("s_waitcnt vmcnt(3)" ::: "memory");                      \
      } else {                                                                \
        asm volatile("s_waitcnt vmcnt(0)" ::: "memory");                      \
      }                                                                       \
      __builtin_amdgcn_s_barrier();                                           \
      __builtin_amdgcn_sched_barrier(0);                                      \
      if (k0 + 64 < DD) {                                                     \
        int nb = cb + 2; if (nb >= 3) nb -= 3;                                \
        GSTAGE_O(Ag, Bg, nb, k0 + 64);                                        \
      }                                                                       \
      const char* Ac = (const char*)&As[cb][0][0];                            \
      const char* Bc = (const char*)&Bs[cb][0][0];                            \
      short8 af[4], bf[2];                                                    \
      _Pragma("unroll")                                                       \
      for (int m = 0; m < 4; ++m)                                             \
        af[m] = *(const short8*)(Ac + (wr * 64 + m * 16 + r16) * 64 +         \
                                 ((g * 16) ^ fsw));                           \
      _Pragma("unroll")                                                       \
      for (int n = 0; n < 2; ++n)                                             \
        bf[n] = *(const short8*)(Bc + (wc * 32 + n * 16 + r16) * 64 +         \
                                 ((g * 16) ^ fsw));                           \
      _Pragma("unroll")                                                       \
      for (int m = 0; m < 4; ++m)                                             \
        _Pragma("unroll")                                                     \
        for (int n = 0; n < 2; ++n) acc[m][n] = mfma16(af[m], bf[n], acc[m][n]); \
      cb = (cb + 1 == 3) ? 0 : cb + 1;                                        \
    }                                                                         \
  }

#define GSTAGE_O(Ag, Bg, buf, k0)                                             \
  {                                                                           \
    _Pragma("unroll")                                                         \
    for (int i = 0; i < 2; ++i)                                               \
      gload_lds16(Ag + (size_t)(row0 + i * 64 + (t >> 2)) * (DD * 2) +        \
                      (k0) * 2 + cs,                                          \
                  (char*)&As[buf][0][0] + i * 4096 + t * 16);                 \
    gload_lds16(Bg + (size_t)(col0 + (t >> 2)) * (DD * 2) + (k0) * 2 + cs,    \
                (char*)&Bs[buf][0][0] + t * 16);                              \
  }

// Fused QKV projection. Q output is PRE-SCALED by 1/sqrt(64)*log2(e).
__global__ __launch_bounds__(256) void gemm_qkv(
    const ushort* __restrict__ A, const ushort* __restrict__ wt,
    const float* __restrict__ bq, const float* __restrict__ bk,
    const float* __restrict__ bv, ushort* __restrict__ qb,
    ushort* __restrict__ kb, ushort* __restrict__ vt) {
  __shared__ ushort As[3][128][32];
  __shared__ ushort Bs[3][128][32];
  const int t = threadIdx.x;
  const int lane = t & 63;
  const int w = t >> 6, wr = w >> 1, wc = w & 1;
  const int r16 = lane & 15, g = lane >> 4;
  const int row0 = blockIdx.x * 128;
  const int mat = blockIdx.y >> 3;
  const int col0 = (blockIdx.y & 7) * 128;
  const char* Ag = (const char*)A;
  const char* Bg = (const char*)(wt + (size_t)mat * DD * DD);
  const float* bias = (mat == 0) ? bq : (mat == 1) ? bk : bv;
  const float scl = (mat == 0) ? 0.125f * 1.44269504f : 1.0f;

  GEMM_CORE(Ag, Bg)

#pragma unroll
  for (int n = 0; n < 4; ++n) {
    const int c = col0 + wc * 64 + n * 16 + r16;
    const float bc = bias[c];
#pragma unroll
    for (int m = 0; m < 4; ++m) {
      const int rbase = row0 + wr * 64 + m * 16 + g * 4;
      if (mat < 2) {
        ushort* outb = (mat == 0) ? qb : kb;
#pragma unroll
        for (int e = 0; e < 4; ++e)
          outb[(size_t)(rbase + e) * DD + c] = f2bf((acc[m][n][e] + bc) * scl);
      } else {
        uint2 st;
        st.x = cvt_pk_bf16(acc[m][n][0] + bc, acc[m][n][1] + bc);
        st.y = cvt_pk_bf16(acc[m][n][2] + bc, acc[m][n][3] + bc);
        const size_t vrow = (size_t)((rbase >> 11) * HH + (c >> 6)) * DQK + (c & 63);
        *(uint2*)(vt + vrow * SS + (rbase & 2047)) = st;
      }
    }
  }
}

// Output projection: att @ Wo + bo + x -> fp32 out. 128x64 tiles, 512 blocks.
__global__ __launch_bounds__(256) void gemm_o(
    const ushort* __restrict__ A, const ushort* __restrict__ Bt,
    const float* __restrict__ bias, const float* __restrict__ resid,
    float* __restrict__ outf) {
  __shared__ ushort As[3][128][32];
  __shared__ ushort Bs[3][64][32];
  const int t = threadIdx.x;
  const int lane = t & 63;
  const int w = t >> 6, wr = w >> 1, wc = w & 1;
  const int r16 = lane & 15, g = lane >> 4;
  const int row0 = blockIdx.x * 128;
  const int col0 = blockIdx.y * 64;
  const char* Ag = (const char*)A;
  const char* Bg = (const char*)Bt;

  GEMM_CORE_O(Ag, Bg)

#pragma unroll
  for (int n = 0; n < 2; ++n) {
    const int c = col0 + wc * 32 + n * 16 + r16;
    const float bc = bias[c];
#pragma unroll
    for (int m = 0; m < 4; ++m) {
      const int rbase = row0 + wr * 64 + m * 16 + g * 4;
#pragma unroll
      for (int e = 0; e < 4; ++e) {
        const size_t idx = (size_t)(rbase + e) * DD + c;
        outf[idx] = acc[m][n][e] + bc + resid[idx];
      }
    }
  }
}

// ---------------------------------------------------------------------------
// MFMA flash attention (causal). Round-8 control flow (1024 blocks, balanced
// {31-m, m, 23-m, 8+m} per-CU map, 32KB double-buffer, one vmcnt(0)+barrier
// per tile) with the per-tile VALU stripped:
//  - tile loop unrolled x2: literal LDS buffer offsets (0/8192), no cur flip
//  - all 16 ds_read offsets precomputed once (registers + imm buffer offset)
//  - staging uses 4 per-thread base pointers + affine tile offsets
//  - causal mask code only in the odd slot / odd tail (even tiles provably
//    non-diagonal)
// Key relabeling keeps P in registers (C/D lane layout == PV B-frag layout).
// ---------------------------------------------------------------------------
__global__ __launch_bounds__(256) void attn_mfma(const ushort* __restrict__ Q,
                                                 const ushort* __restrict__ K,
                                                 const ushort* __restrict__ Vt,
                                                 ushort* __restrict__ O) {
  __shared__ ushort Ks[2][64][64];  // [buf][key][d]  128B rows, swizzled
  __shared__ ushort Vs[2][64][64];  // [buf][dq][key] 128B rows, swizzled

  const int t = threadIdx.x, lane = t & 63, ww = t >> 6;
  const int r16 = lane & 15, g = lane >> 4;

  const int bid = blockIdx.x;                    // 1024 blocks
  const int xcd = bid & 7;
  const int bh = xcd * 4 + ((bid >> 3) & 3);     // 4 heads per XCD
  const int m = (bid >> 5) & 7;
  const int j = bid >> 8;                        // 0..3
  const int qb = (j == 0) ? (31 - m) : (j == 1) ? m : (j == 2) ? (23 - m) : (8 + m);
  const int b = bh >> 4, h = bh & 15;
  const size_t tokbase = (size_t)b * SS;
  const size_t hoff = (size_t)h * DQK;
  const int q0 = qb * 64 + ww * 16;
  const int nt = qb + 1;

  // --- staging bases (computed once; per-tile offset is affine) ---
  const int srow = t >> 3;                       // 0..31
  const int scol = (t & 7) * 16;
  const int Cs = scol ^ (((srow & 3) | ((srow >> 1) & 4)) << 4);  // bit3 of R==bit3 of srow
  const char* Kb = (const char*)(K + tokbase * DD + hoff);
  const char* Vb = (const char*)(Vt + (size_t)bh * DQK * SS);
  const char* kbase0 = Kb + (size_t)srow * (DD * 2) + Cs;
  const char* kbase1 = Kb + (size_t)(srow + 32) * (DD * 2) + Cs;
  const char* vbase0 = Vb + (size_t)srow * (SS * 2) + Cs;
  const char* vbase1 = Vb + (size_t)(srow + 32) * (SS * 2) + Cs;
  char* ksd = (char*)&Ks[0][0][0] + ww * 1024;   // wave-uniform LDS dests
  char* vsd = (char*)&Vs[0][0][0] + ww * 1024;

#define STAGE(BOFF, TILE)                                                     \
  {                                                                           \
    const size_t ko = (size_t)(TILE) << 17;  /* tile*64*DD*2 */               \
    const size_t vo = (size_t)(TILE) << 7;   /* tile*64*2   */                \
    gload_lds16(kbase0 + ko, ksd + (BOFF));                                   \
    gload_lds16(kbase1 + ko, ksd + (BOFF) + 4096);                            \
    gload_lds16(vbase0 + vo, vsd + (BOFF));                                   \
    gload_lds16(vbase1 + vo, vsd + (BOFF) + 4096);                            \
  }

  // --- precomputed LDS read offsets (registers; buffer picked via imm) ---
  const int sw = ((r16 & 3) | ((r16 >> 1) & 4)) << 4;  // V-read swz bits {0,1,3}
  const int rlo = (r16 & 3) + ((r16 >> 2) << 3);       // K-row permutation base
  int offk[4][2], offv[4][2];
#pragma unroll
  for (int t2 = 0; t2 < 4; ++t2) {
    const int kk = rlo + (t2 & 1) * 4 + (t2 >> 1) * 32;
    const int sk = ((kk & 3) | ((kk >> 1) & 4)) << 4;
    offk[t2][0] = kk * 128 + ((g * 16) ^ sk);
    offk[t2][1] = kk * 128 + ((64 + g * 16) ^ sk);
  }
#pragma unroll
  for (int dt = 0; dt < 4; ++dt) {
    offv[dt][0] = (dt * 16 + r16) * 128 + ((g * 16) ^ sw);
    offv[dt][1] = (dt * 16 + r16) * 128 + ((64 + g * 16) ^ sw);
  }
  const char* KsB = (const char*)&Ks[0][0][0];
  const char* VsB = (const char*)&Vs[0][0][0];

  // Q fragments (B-operand, pre-scaled into exp2 domain by gemm_qkv)
  const short8 qc0 = *(const short8*)(Q + (tokbase + q0 + r16) * DD + hoff + g * 8);
  const short8 qc1 = *(const short8*)(Q + (tokbase + q0 + r16) * DD + hoff + 32 + g * 8);

  f32x4 o[4];
#pragma unroll
  for (int dt = 0; dt < 4; ++dt) o[dt] = (f32x4){0.f, 0.f, 0.f, 0.f};
  float rm = -INFINITY, rl = 0.f;                // rl is a per-lane PARTIAL

#define COMPUTE(BOFF, DOMASK, TLOC)                                           \
  {                                                                           \
    f32x4 s4[4];                                                              \
    __builtin_amdgcn_s_setprio(1);                                            \
    _Pragma("unroll")                                                         \
    for (int t2 = 0; t2 < 4; ++t2) {                                          \
      const short8 k0 = *(const short8*)(KsB + (BOFF) + offk[t2][0]);         \
      const short8 k1 = *(const short8*)(KsB + (BOFF) + offk[t2][1]);         \
      f32x4 s = mfma16(k0, qc0, (f32x4){0.f, 0.f, 0.f, 0.f});                 \
      s4[t2] = mfma16(k1, qc1, s);                                            \
    }                                                                         \
    __builtin_amdgcn_s_setprio(0);                                            \
    if (DOMASK) {                                                             \
      const int thrl = q0 + r16 - g * 8 - (TLOC) * 64;                        \
      _Pragma("unroll")                                                       \
      for (int t2 = 0; t2 < 4; ++t2) {                                        \
        const int bb = (t2 & 1) * 4 + (t2 >> 1) * 32;                         \
        _Pragma("unroll")                                                     \
        for (int r = 0; r < 4; ++r)                                           \
          s4[t2][r] = (bb + r <= thrl) ? s4[t2][r] : -INFINITY;               \
      }                                                                       \
    }                                                                         \
    float mx = fmaxf(                                                         \
        fmaxf(fmaxf(fmaxf(s4[0][0], s4[0][1]), fmaxf(s4[0][2], s4[0][3])),    \
              fmaxf(fmaxf(s4[1][0], s4[1][1]), fmaxf(s4[1][2], s4[1][3]))),   \
        fmaxf(fmaxf(fmaxf(s4[2][0], s4[2][1]), fmaxf(s4[2][2], s4[2][3])),    \
              fmaxf(fmaxf(s4[3][0], s4[3][1]), fmaxf(s4[3][2], s4[3][3]))));  \
    if (!__all(mx - rm <= 8.f)) {                                             \
      float mf = fmaxf(mx, __shfl_xor(mx, 16));                               \
      mf = fmaxf(mf, __shfl_xor(mf, 32));                                     \
      const float mn = fmaxf(rm, mf);                                         \
      const float sc = __builtin_amdgcn_exp2f(rm - mn);                       \
      rl *= sc;                                                               \
      _Pragma("unroll")                                                       \
      for (int dt = 0; dt < 4; ++dt) o[dt] *= sc;                             \
      rm = mn;                                                                \
    }                                                                         \
    union { unsigned u[4]; short8 s; } pbu[2];                                \
    _Pragma("unroll")                                                         \
    for (int t2 = 0; t2 < 4; ++t2) {                                          \
      const float p0 = __builtin_amdgcn_exp2f(s4[t2][0] - rm);                \
      const float p1 = __builtin_amdgcn_exp2f(s4[t2][1] - rm);                \
      const float p2 = __builtin_amdgcn_exp2f(s4[t2][2] - rm);                \
      const float p3 = __builtin_amdgcn_exp2f(s4[t2][3] - rm);                \
      rl += (p0 + p1) + (p2 + p3);                                            \
      pbu[t2 >> 1].u[(t2 & 1) * 2 + 0] = cvt_pk_bf16(p0, p1);                 \
      pbu[t2 >> 1].u[(t2 & 1) * 2 + 1] = cvt_pk_bf16(p2, p3);                 \
    }                                                                         \
    __builtin_amdgcn_s_setprio(1);                                            \
    _Pragma("unroll")                                                         \
    for (int kc = 0; kc < 2; ++kc)                                            \
      _Pragma("unroll")                                                       \
      for (int dt = 0; dt < 4; ++dt) {                                        \
        const short8 vf = *(const short8*)(VsB + (BOFF) + offv[dt][kc]);      \
        o[dt] = mfma16(vf, pbu[kc].s, o[dt]);                                 \
      }                                                                       \
    __builtin_amdgcn_s_setprio(0);                                            \
  }

#define WAITBAR                                                               \
  __builtin_amdgcn_sched_barrier(0);                                          \
  asm volatile("s_waitcnt vmcnt(0)" ::: "memory");                            \
  __builtin_amdgcn_s_barrier();                                               \
  __builtin_amdgcn_sched_barrier(0);

  STAGE(0, 0);
  int tt = 0;
#pragma unroll 1
  for (; tt + 2 <= nt; tt += 2) {
    // even tile tt (buf0) -- provably non-diagonal (tt <= nt-2)
    WAITBAR;                                     // drains S(tt) only
    STAGE(8192, tt + 1);                         // -> buf1
    COMPUTE(0, false, 0);
    // odd tile tt+1 (buf1) -- diagonal iff tt+2 == nt
    WAITBAR;                                     // drains S(tt+1) only
    {
      int pj = tt + 2; if (pj >= nt) pj = 0;     // clamped prefetch (unused if wrap)
      STAGE(0, pj);                              // -> buf0
    }
    COMPUTE(8192, (tt + 2 == nt), (tt + 1));
  }
  if (tt < nt) {                                 // odd-nt tail: diagonal tile
    WAITBAR;
    COMPUTE(0, true, tt);
  }
#undef STAGE
#undef COMPUTE
#undef WAITBAR

  // --- cross-lane l-reduction, once ---
  rl += __shfl_xor(rl, 16);
  rl += __shfl_xor(rl, 32);
  const float inv = 1.0f / rl;
#pragma unroll
  for (int dt = 0; dt < 4; ++dt) {
    uint2 st;
    st.x = cvt_pk_bf16(o[dt][0] * inv, o[dt][1] * inv);
    st.y = cvt_pk_bf16(o[dt][2] * inv, o[dt][3] * inv);
    *(uint2*)(O + (tokbase + q0 + r16) * DD + hoff + dt * 16 + g * 4) = st;
  }
}

// ---------------------------------------------------------------------------
// Launch: prep (LN + wtrans fused) -> fused QKV GEMM -> attn -> O-GEMM.
// ws: xn 8MB | q 8MB | k 8MB | vt 8MB | att 8MB | wt 16MB  (56MB)
// ---------------------------------------------------------------------------
extern "C" void kernel_launch(void* const* d_in, const int* in_sizes, int n_in,
                              void* d_out, int out_size, void* d_ws, size_t ws_size,
                              hipStream_t stream) {
  const float* x    = (const float*)d_in[0];
  const float* ln_g = (const float*)d_in[1];
  const float* ln_b = (const float*)d_in[2];
  const float* Wq   = (const float*)d_in[3];
  const float* bq   = (const float*)d_in[4];
  const float* Wk   = (const float*)d_in[5];
  const float* bk   = (const float*)d_in[6];
  const float* Wv   = (const float*)d_in[7];
  const float* bv   = (const float*)d_in[8];
  const float* Wo   = (const float*)d_in[9];
  const float* bo   = (const float*)d_in[10];
  float* out = (float*)d_out;

  ushort* ws  = (ushort*)d_ws;
  ushort* xn  = ws;
  ushort* qb  = xn + NE;
  ushort* kb  = qb + NE;
  ushort* vt  = kb + NE;
  ushort* ab  = vt + NE;
  ushort* wt  = ab + NE;               // 4 x [1024][1024] bf16
  ushort* wot = wt + (size_t)3 * DD * DD;

  prep<<<NROWS + 1024, 256, 0, stream>>>(x, ln_g, ln_b, xn, Wq, Wk, Wv, Wo, wt);

  gemm_qkv<<<dim3(NROWS / 128, 24), 256, 0, stream>>>(xn, wt, bq, bk, bv,
                                                      qb, kb, vt);

  attn_mfma<<<BB * HH * (SS / 64), 256, 0, stream>>>(qb, kb, vt, ab);

  gemm_o<<<dim3(NROWS / 128, DD / 64), 256, 0, stream>>>(ab, wot, bo, x, out);
}

// Round 11
// 102.987 us; speedup vs baseline: 1.0543x; 1.0063x over previous
//
#include <hip/hip_runtime.h>
#include <math.h>

// Problem constants: B=2, S=2048, D=1024, H=16, DQ=64
#define BB 2
#define SS 2048
#define DD 1024
#define HH 16
#define DQK 64
#define NROWS (BB * SS)
#define NE ((size_t)BB * SS * DD)   // 4,194,304

using short8 = __attribute__((ext_vector_type(8))) short;
using f32x4  = __attribute__((ext_vector_type(4))) float;

__device__ __forceinline__ ushort f2bf(float f) {
  union { float f; unsigned u; } c; c.f = f;
  return (ushort)((c.u + 0x7fffu + ((c.u >> 16) & 1u)) >> 16);
}

__device__ __forceinline__ unsigned cvt_pk_bf16(float lo, float hi) {
  unsigned r;
  asm("v_cvt_pk_bf16_f32 %0, %1, %2" : "=v"(r) : "v"(lo), "v"(hi));
  return r;
}

__device__ __forceinline__ f32x4 mfma16(short8 a, short8 b, f32x4 c) {
  return __builtin_amdgcn_mfma_f32_16x16x32_bf16(a, b, c, 0, 0, 0);
}

typedef __attribute__((address_space(1))) const unsigned gas_u32;
typedef __attribute__((address_space(3))) unsigned las_u32;
__device__ __forceinline__ void gload_lds16(const void* g, void* l) {
  __builtin_amdgcn_global_load_lds((gas_u32*)g, (las_u32*)l, 16, 0, 0);
}

// ---------------------------------------------------------------------------
// Fused prepass: blocks [0,4096) do LayerNorm->bf16 (one row each);
// blocks [4096,5120) transpose+cast the 4 weight matrices to Wt[N][K] bf16.
// ---------------------------------------------------------------------------
__global__ __launch_bounds__(256) void prep(const float* __restrict__ x,
                                            const float* __restrict__ g,
                                            const float* __restrict__ bta,
                                            ushort* __restrict__ xn,
                                            const float* __restrict__ Wq,
                                            const float* __restrict__ Wk,
                                            const float* __restrict__ Wv,
                                            const float* __restrict__ Wo,
                                            ushort* __restrict__ wt) {
  __shared__ float tile[64][65];
  const int t = threadIdx.x;
  if (blockIdx.x < NROWS) {
    const int row = blockIdx.x;
    float4 v = ((const float4*)(x + (size_t)row * DD))[t];
    float s  = v.x + v.y + v.z + v.w;
    float ss = v.x * v.x + v.y * v.y + v.z * v.z + v.w * v.w;
#pragma unroll
    for (int off = 32; off > 0; off >>= 1) {
      s  += __shfl_xor(s, off);
      ss += __shfl_xor(ss, off);
    }
    const int wid = t >> 6, lane = t & 63;
    if (lane == 0) { tile[0][wid] = s; tile[0][4 + wid] = ss; }
    __syncthreads();
    const float stot  = tile[0][0] + tile[0][1] + tile[0][2] + tile[0][3];
    const float sstot = tile[0][4] + tile[0][5] + tile[0][6] + tile[0][7];
    const float mu  = stot * (1.0f / DD);
    const float var = sstot * (1.0f / DD) - mu * mu;
    const float inv = rsqrtf(var + 1e-5f);
    const float4 g4 = ((const float4*)g)[t];
    const float4 b4 = ((const float4*)bta)[t];
    ushort4 o;
    o.x = f2bf((v.x - mu) * inv * g4.x + b4.x);
    o.y = f2bf((v.y - mu) * inv * g4.y + b4.y);
    o.z = f2bf((v.z - mu) * inv * g4.z + b4.z);
    o.w = f2bf((v.w - mu) * inv * g4.w + b4.w);
    ((ushort4*)(xn + (size_t)row * DD))[t] = o;
  } else {
    const int wb = blockIdx.x - NROWS;        // 0..1023
    const int z = wb >> 8;                    // matrix id
    const int k0 = (wb & 15) * 64, n0 = ((wb >> 4) & 15) * 64;
    const float* W = (z == 0) ? Wq : (z == 1) ? Wk : (z == 2) ? Wv : Wo;
    ushort* dst = wt + (size_t)z * DD * DD;
    const int tr = t >> 4, tc = (t & 15) * 4;
#pragma unroll
    for (int rr = 0; rr < 64; rr += 16) {
      float4 v = *(const float4*)(W + (size_t)(k0 + rr + tr) * DD + n0 + tc);
      tile[rr + tr][tc + 0] = v.x;
      tile[rr + tr][tc + 1] = v.y;
      tile[rr + tr][tc + 2] = v.z;
      tile[rr + tr][tc + 3] = v.w;
    }
    __syncthreads();
#pragma unroll
    for (int rr = 0; rr < 64; rr += 16) {
      const int n = rr + tr;
      ushort4 o;
      o.x = f2bf(tile[tc + 0][n]);
      o.y = f2bf(tile[tc + 1][n]);
      o.z = f2bf(tile[tc + 2][n]);
      o.w = f2bf(tile[tc + 3][n]);
      *(ushort4*)(dst + (size_t)(n0 + n) * DD + k0 + tc) = o;
    }
  }
}

// ---------------------------------------------------------------------------
// 128x128 GEMM core. 4 waves, BK=32, triple-buffered global_load_lds with
// counted vmcnt(4) + raw s_barrier. Read-side XOR (r16>>1)&3 (row bits 1-2).
// ---------------------------------------------------------------------------
#define GEMM_CORE(Ag, Bg)                                                     \
  f32x4 acc[4][4];                                                            \
  _Pragma("unroll")                                                           \
  for (int m = 0; m < 4; ++m)                                                 \
    _Pragma("unroll")                                                         \
    for (int n = 0; n < 4; ++n) acc[m][n] = (f32x4){0.f, 0.f, 0.f, 0.f};     \
  const int cs = ((t & 3) * 16) ^ (((t >> 3) & 3) * 16);                      \
  const int fsw = ((r16 >> 1) & 3) * 16;                                      \
  {                                                                           \
    GSTAGE(Ag, Bg, 0, 0);                                                     \
    GSTAGE(Ag, Bg, 1, 32);                                                    \
    int cb = 0;                                                               \
    for (int k0 = 0; k0 < DD; k0 += 32) {                                     \
      __builtin_amdgcn_sched_barrier(0);                                      \
      if (k0 + 32 < DD) {                                                     \
        asm volatile("s_waitcnt vmcnt(4)" ::: "memory");                      \
      } else {                                                                \
        asm volatile("s_waitcnt vmcnt(0)" ::: "memory");                      \
      }                                                                       \
      __builtin_amdgcn_s_barrier();                                           \
      __builtin_amdgcn_sched_barrier(0);                                      \
      if (k0 + 64 < DD) {                                                     \
        int nb = cb + 2; if (nb >= 3) nb -= 3;                                \
        GSTAGE(Ag, Bg, nb, k0 + 64);                                          \
      }                                                                       \
      const char* Ac = (const char*)&As[cb][0][0];                            \
      const char* Bc = (const char*)&Bs[cb][0][0];                            \
      short8 af[4], bf[4];                                                    \
      _Pragma("unroll")                                                       \
      for (int m = 0; m < 4; ++m)                                             \
        af[m] = *(const short8*)(Ac + (wr * 64 + m * 16 + r16) * 64 +         \
                                 ((g * 16) ^ fsw));                           \
      _Pragma("unroll")                                                       \
      for (int n = 0; n < 4; ++n)                                             \
        bf[n] = *(const short8*)(Bc + (wc * 64 + n * 16 + r16) * 64 +         \
                                 ((g * 16) ^ fsw));                           \
      _Pragma("unroll")                                                       \
      for (int m = 0; m < 4; ++m)                                             \
        _Pragma("unroll")                                                     \
        for (int n = 0; n < 4; ++n) acc[m][n] = mfma16(af[m], bf[n], acc[m][n]); \
      cb = (cb + 1 == 3) ? 0 : cb + 1;                                        \
    }                                                                         \
  }

#define GSTAGE(Ag, Bg, buf, k0)                                               \
  {                                                                           \
    _Pragma("unroll")                                                         \
    for (int i = 0; i < 2; ++i) {                                             \
      gload_lds16(Ag + (size_t)(row0 + i * 64 + (t >> 2)) * (DD * 2) +        \
                      (k0) * 2 + cs,                                          \
                  (char*)&As[buf][0][0] + i * 4096 + t * 16);                 \
      gload_lds16(Bg + (size_t)(col0 + i * 64 + (t >> 2)) * (DD * 2) +        \
                      (k0) * 2 + cs,                                          \
                  (char*)&Bs[buf][0][0] + i * 4096 + t * 16);                 \
    }                                                                         \
  }

// 128x64 GEMM core (for gemm_o): 512 blocks -> 2 blocks/CU, 2 waves/SIMD.
#define GEMM_CORE_O(Ag, Bg)                                                   \
  f32x4 acc[4][2];                                                            \
  _Pragma("unroll")                                                           \
  for (int m = 0; m < 4; ++m)                                                 \
    _Pragma("unroll")                                                         \
    for (int n = 0; n < 2; ++n) acc[m][n] = (f32x4){0.f, 0.f, 0.f, 0.f};     \
  const int cs = ((t & 3) * 16) ^ (((t >> 3) & 3) * 16);                      \
  const int fsw = ((r16 >> 1) & 3) * 16;                                      \
  {                                                                           \
    GSTAGE_O(Ag, Bg, 0, 0);                                                   \
    GSTAGE_O(Ag, Bg, 1, 32);                                                  \
    int cb = 0;                                                               \
    for (int k0 = 0; k0 < DD; k0 += 32) {                                     \
      __builtin_amdgcn_sched_barrier(0);                                      \
      if (k0 + 32 < DD) {                                                     \
        asm volatile("s_waitcnt vmcnt(3)" ::: "memory");                      \
      } else {                                                                \
        asm volatile("s_waitcnt vmcnt(0)" ::: "memory");                      \
      }                                                                       \
      __builtin_amdgcn_s_barrier();                                           \
      __builtin_amdgcn_sched_barrier(0);                                      \
      if (k0 + 64 < DD) {                                                     \
        int nb = cb + 2; if (nb >= 3) nb -= 3;                                \
        GSTAGE_O(Ag, Bg, nb, k0 + 64);                                        \
      }                                                                       \
      const char* Ac = (const char*)&As[cb][0][0];                            \
      const char* Bc = (const char*)&Bs[cb][0][0];                            \
      short8 af[4], bf[2];                                                    \
      _Pragma("unroll")                                                       \
      for (int m = 0; m < 4; ++m)                                             \
        af[m] = *(const short8*)(Ac + (wr * 64 + m * 16 + r16) * 64 +         \
                                 ((g * 16) ^ fsw));                           \
      _Pragma("unroll")                                                       \
      for (int n = 0; n < 2; ++n)                                             \
        bf[n] = *(const short8*)(Bc + (wc * 32 + n * 16 + r16) * 64 +         \
                                 ((g * 16) ^ fsw));                           \
      _Pragma("unroll")                                                       \
      for (int m = 0; m < 4; ++m)                                             \
        _Pragma("unroll")                                                     \
        for (int n = 0; n < 2; ++n) acc[m][n] = mfma16(af[m], bf[n], acc[m][n]); \
      cb = (cb + 1 == 3) ? 0 : cb + 1;                                        \
    }                                                                         \
  }

#define GSTAGE_O(Ag, Bg, buf, k0)                                             \
  {                                                                           \
    _Pragma("unroll")                                                         \
    for (int i = 0; i < 2; ++i)                                               \
      gload_lds16(Ag + (size_t)(row0 + i * 64 + (t >> 2)) * (DD * 2) +        \
                      (k0) * 2 + cs,                                          \
                  (char*)&As[buf][0][0] + i * 4096 + t * 16);                 \
    gload_lds16(Bg + (size_t)(col0 + (t >> 2)) * (DD * 2) + (k0) * 2 + cs,    \
                (char*)&Bs[buf][0][0] + t * 16);                              \
  }

// Fused QKV projection. Q output is PRE-SCALED by 1/sqrt(64)*log2(e).
__global__ __launch_bounds__(256, 3) void gemm_qkv(
    const ushort* __restrict__ A, const ushort* __restrict__ wt,
    const float* __restrict__ bq, const float* __restrict__ bk,
    const float* __restrict__ bv, ushort* __restrict__ qb,
    ushort* __restrict__ kb, ushort* __restrict__ vt) {
  __shared__ ushort As[3][128][32];
  __shared__ ushort Bs[3][128][32];
  const int t = threadIdx.x;
  const int lane = t & 63;
  const int w = t >> 6, wr = w >> 1, wc = w & 1;
  const int r16 = lane & 15, g = lane >> 4;
  const int row0 = blockIdx.x * 128;
  const int mat = blockIdx.y >> 3;
  const int col0 = (blockIdx.y & 7) * 128;
  const char* Ag = (const char*)A;
  const char* Bg = (const char*)(wt + (size_t)mat * DD * DD);
  const float* bias = (mat == 0) ? bq : (mat == 1) ? bk : bv;
  const float scl = (mat == 0) ? 0.125f * 1.44269504f : 1.0f;

  GEMM_CORE(Ag, Bg)

#pragma unroll
  for (int n = 0; n < 4; ++n) {
    const int c = col0 + wc * 64 + n * 16 + r16;
    const float bc = bias[c];
#pragma unroll
    for (int m = 0; m < 4; ++m) {
      const int rbase = row0 + wr * 64 + m * 16 + g * 4;
      if (mat < 2) {
        ushort* outb = (mat == 0) ? qb : kb;
#pragma unroll
        for (int e = 0; e < 4; ++e)
          outb[(size_t)(rbase + e) * DD + c] = f2bf((acc[m][n][e] + bc) * scl);
      } else {
        uint2 st;
        st.x = cvt_pk_bf16(acc[m][n][0] + bc, acc[m][n][1] + bc);
        st.y = cvt_pk_bf16(acc[m][n][2] + bc, acc[m][n][3] + bc);
        const size_t vrow = (size_t)((rbase >> 11) * HH + (c >> 6)) * DQK + (c & 63);
        *(uint2*)(vt + vrow * SS + (rbase & 2047)) = st;
      }
    }
  }
}

// Output projection: att @ Wo + bo + x -> fp32 out. 128x64 tiles, 512 blocks.
__global__ __launch_bounds__(256, 2) void gemm_o(
    const ushort* __restrict__ A, const ushort* __restrict__ Bt,
    const float* __restrict__ bias, const float* __restrict__ resid,
    float* __restrict__ outf) {
  __shared__ ushort As[3][128][32];
  __shared__ ushort Bs[3][64][32];
  const int t = threadIdx.x;
  const int lane = t & 63;
  const int w = t >> 6, wr = w >> 1, wc = w & 1;
  const int r16 = lane & 15, g = lane >> 4;
  const int row0 = blockIdx.x * 128;
  const int col0 = blockIdx.y * 64;
  const char* Ag = (const char*)A;
  const char* Bg = (const char*)Bt;

  GEMM_CORE_O(Ag, Bg)

#pragma unroll
  for (int n = 0; n < 2; ++n) {
    const int c = col0 + wc * 32 + n * 16 + r16;
    const float bc = bias[c];
#pragma unroll
    for (int m = 0; m < 4; ++m) {
      const int rbase = row0 + wr * 64 + m * 16 + g * 4;
#pragma unroll
      for (int e = 0; e < 4; ++e) {
        const size_t idx = (size_t)(rbase + e) * DD + c;
        outf[idx] = acc[m][n][e] + bc + resid[idx];
      }
    }
  }
}

// ---------------------------------------------------------------------------
// MFMA flash attention (causal). Round-10 structure (1024 blocks, balanced
// {31-m, m, 23-m, 8+m} per-CU map, 32KB double-buffer, x2-unrolled tile loop
// with literal buffer offsets, precomputed LDS read offsets, affine staging).
// NEW: __launch_bounds__(256, 4) -> VGPR cap 128 (was 64): the precomputed
// state actually stays in registers instead of being rematerialized per tile.
// ---------------------------------------------------------------------------
__global__ __launch_bounds__(256, 4) void attn_mfma(const ushort* __restrict__ Q,
                                                    const ushort* __restrict__ K,
                                                    const ushort* __restrict__ Vt,
                                                    ushort* __restrict__ O) {
  __shared__ ushort Ks[2][64][64];  // [buf][key][d]  128B rows, swizzled
  __shared__ ushort Vs[2][64][64];  // [buf][dq][key] 128B rows, swizzled

  const int t = threadIdx.x, lane = t & 63, ww = t >> 6;
  const int r16 = lane & 15, g = lane >> 4;

  const int bid = blockIdx.x;                    // 1024 blocks
  const int xcd = bid & 7;
  const int bh = xcd * 4 + ((bid >> 3) & 3);     // 4 heads per XCD
  const int m = (bid >> 5) & 7;
  const int j = bid >> 8;                        // 0..3
  const int qb = (j == 0) ? (31 - m) : (j == 1) ? m : (j == 2) ? (23 - m) : (8 + m);
  const int b = bh >> 4, h = bh & 15;
  const size_t tokbase = (size_t)b * SS;
  const size_t hoff = (size_t)h * DQK;
  const int q0 = qb * 64 + ww * 16;
  const int nt = qb + 1;

  // --- staging bases (computed once; per-tile offset is affine) ---
  const int srow = t >> 3;                       // 0..31
  const int scol = (t & 7) * 16;
  const int Cs = scol ^ (((srow & 3) | ((srow >> 1) & 4)) << 4);
  const char* Kb = (const char*)(K + tokbase * DD + hoff);
  const char* Vb = (const char*)(Vt + (size_t)bh * DQK * SS);
  const char* kbase0 = Kb + (size_t)srow * (DD * 2) + Cs;
  const char* kbase1 = Kb + (size_t)(srow + 32) * (DD * 2) + Cs;
  const char* vbase0 = Vb + (size_t)srow * (SS * 2) + Cs;
  const char* vbase1 = Vb + (size_t)(srow + 32) * (SS * 2) + Cs;
  char* ksd = (char*)&Ks[0][0][0] + ww * 1024;   // wave-uniform LDS dests
  char* vsd = (char*)&Vs[0][0][0] + ww * 1024;

#define STAGE(BOFF, TILE)                                                     \
  {                                                                           \
    const size_t ko = (size_t)(TILE) << 17;  /* tile*64*DD*2 */               \
    const size_t vo = (size_t)(TILE) << 7;   /* tile*64*2   */                \
    gload_lds16(kbase0 + ko, ksd + (BOFF));                                   \
    gload_lds16(kbase1 + ko, ksd + (BOFF) + 4096);                            \
    gload_lds16(vbase0 + vo, vsd + (BOFF));                                   \
    gload_lds16(vbase1 + vo, vsd + (BOFF) + 4096);                            \
  }

  // --- precomputed LDS read offsets (registers; buffer picked via imm) ---
  const int sw = ((r16 & 3) | ((r16 >> 1) & 4)) << 4;  // V-read swz bits {0,1,3}
  const int rlo = (r16 & 3) + ((r16 >> 2) << 3);       // K-row permutation base
  int offk[4][2], offv[4][2];
#pragma unroll
  for (int t2 = 0; t2 < 4; ++t2) {
    const int kk = rlo + (t2 & 1) * 4 + (t2 >> 1) * 32;
    const int sk = ((kk & 3) | ((kk >> 1) & 4)) << 4;
    offk[t2][0] = kk * 128 + ((g * 16) ^ sk);
    offk[t2][1] = kk * 128 + ((64 + g * 16) ^ sk);
  }
#pragma unroll
  for (int dt = 0; dt < 4; ++dt) {
    offv[dt][0] = (dt * 16 + r16) * 128 + ((g * 16) ^ sw);
    offv[dt][1] = (dt * 16 + r16) * 128 + ((64 + g * 16) ^ sw);
  }
  const char* KsB = (const char*)&Ks[0][0][0];
  const char* VsB = (const char*)&Vs[0][0][0];

  // Q fragments (B-operand, pre-scaled into exp2 domain by gemm_qkv)
  const short8 qc0 = *(const short8*)(Q + (tokbase + q0 + r16) * DD + hoff + g * 8);
  const short8 qc1 = *(const short8*)(Q + (tokbase + q0 + r16) * DD + hoff + 32 + g * 8);

  f32x4 o[4];
#pragma unroll
  for (int dt = 0; dt < 4; ++dt) o[dt] = (f32x4){0.f, 0.f, 0.f, 0.f};
  float rm = -INFINITY, rl = 0.f;                // rl is a per-lane PARTIAL

#define COMPUTE(BOFF, DOMASK, TLOC)                                           \
  {                                                                           \
    f32x4 s4[4];                                                              \
    __builtin_amdgcn_s_setprio(1);                                            \
    _Pragma("unroll")                                                         \
    for (int t2 = 0; t2 < 4; ++t2) {                                          \
      const short8 k0 = *(const short8*)(KsB + (BOFF) + offk[t2][0]);         \
      const short8 k1 = *(const short8*)(KsB + (BOFF) + offk[t2][1]);         \
      f32x4 s = mfma16(k0, qc0, (f32x4){0.f, 0.f, 0.f, 0.f});                 \
      s4[t2] = mfma16(k1, qc1, s);                                            \
    }                                                                         \
    __builtin_amdgcn_s_setprio(0);                                            \
    if (DOMASK) {                                                             \
      const int thrl = q0 + r16 - g * 8 - (TLOC) * 64;                        \
      _Pragma("unroll")                                                       \
      for (int t2 = 0; t2 < 4; ++t2) {                                        \
        const int bb = (t2 & 1) * 4 + (t2 >> 1) * 32;                         \
        _Pragma("unroll")                                                     \
        for (int r = 0; r < 4; ++r)                                           \
          s4[t2][r] = (bb + r <= thrl) ? s4[t2][r] : -INFINITY;               \
      }                                                                       \
    }                                                                         \
    float mx = fmaxf(                                                         \
        fmaxf(fmaxf(fmaxf(s4[0][0], s4[0][1]), fmaxf(s4[0][2], s4[0][3])),    \
              fmaxf(fmaxf(s4[1][0], s4[1][1]), fmaxf(s4[1][2], s4[1][3]))),   \
        fmaxf(fmaxf(fmaxf(s4[2][0], s4[2][1]), fmaxf(s4[2][2], s4[2][3])),    \
              fmaxf(fmaxf(s4[3][0], s4[3][1]), fmaxf(s4[3][2], s4[3][3]))));  \
    if (!__all(mx - rm <= 8.f)) {                                             \
      float mf = fmaxf(mx, __shfl_xor(mx, 16));                               \
      mf = fmaxf(mf, __shfl_xor(mf, 32));                                     \
      const float mn = fmaxf(rm, mf);                                         \
      const float sc = __builtin_amdgcn_exp2f(rm - mn);                       \
      rl *= sc;                                                               \
      _Pragma("unroll")                                                       \
      for (int dt = 0; dt < 4; ++dt) o[dt] *= sc;                             \
      rm = mn;                                                                \
    }                                                                         \
    union { unsigned u[4]; short8 s; } pbu[2];                                \
    _Pragma("unroll")                                                         \
    for (int t2 = 0; t2 < 4; ++t2) {                                          \
      const float p0 = __builtin_amdgcn_exp2f(s4[t2][0] - rm);                \
      const float p1 = __builtin_amdgcn_exp2f(s4[t2][1] - rm);                \
      const float p2 = __builtin_amdgcn_exp2f(s4[t2][2] - rm);                \
      const float p3 = __builtin_amdgcn_exp2f(s4[t2][3] - rm);                \
      rl += (p0 + p1) + (p2 + p3);                                            \
      pbu[t2 >> 1].u[(t2 & 1) * 2 + 0] = cvt_pk_bf16(p0, p1);                 \
      pbu[t2 >> 1].u[(t2 & 1) * 2 + 1] = cvt_pk_bf16(p2, p3);                 \
    }                                                                         \
    __builtin_amdgcn_s_setprio(1);                                            \
    _Pragma("unroll")                                                         \
    for (int kc = 0; kc < 2; ++kc)                                            \
      _Pragma("unroll")                                                       \
      for (int dt = 0; dt < 4; ++dt) {                                        \
        const short8 vf = *(const short8*)(VsB + (BOFF) + offv[dt][kc]);      \
        o[dt] = mfma16(vf, pbu[kc].s, o[dt]);                                 \
      }                                                                       \
    __builtin_amdgcn_s_setprio(0);                                            \
  }

#define WAITBAR                                                               \
  __builtin_amdgcn_sched_barrier(0);                                          \
  asm volatile("s_waitcnt vmcnt(0)" ::: "memory");                            \
  __builtin_amdgcn_s_barrier();                                               \
  __builtin_amdgcn_sched_barrier(0);

  STAGE(0, 0);
  int tt = 0;
#pragma unroll 1
  for (; tt + 2 <= nt; tt += 2) {
    // even tile tt (buf0) -- provably non-diagonal (tt <= nt-2)
    WAITBAR;                                     // drains S(tt) only
    STAGE(8192, tt + 1);                         // -> buf1
    COMPUTE(0, false, 0);
    // odd tile tt+1 (buf1) -- diagonal iff tt+2 == nt
    WAITBAR;                                     // drains S(tt+1) only
    {
      int pj = tt + 2; if (pj >= nt) pj = 0;     // clamped prefetch (unused if wrap)
      STAGE(0, pj);                              // -> buf0
    }
    COMPUTE(8192, (tt + 2 == nt), (tt + 1));
  }
  if (tt < nt) {                                 // odd-nt tail: diagonal tile
    WAITBAR;
    COMPUTE(0, true, tt);
  }
#undef STAGE
#undef COMPUTE
#undef WAITBAR

  // --- cross-lane l-reduction, once ---
  rl += __shfl_xor(rl, 16);
  rl += __shfl_xor(rl, 32);
  const float inv = 1.0f / rl;
#pragma unroll
  for (int dt = 0; dt < 4; ++dt) {
    uint2 st;
    st.x = cvt_pk_bf16(o[dt][0] * inv, o[dt][1] * inv);
    st.y = cvt_pk_bf16(o[dt][2] * inv, o[dt][3] * inv);
    *(uint2*)(O + (tokbase + q0 + r16) * DD + hoff + dt * 16 + g * 4) = st;
  }
}

// ---------------------------------------------------------------------------
// Launch: prep (LN + wtrans fused) -> fused QKV GEMM -> attn -> O-GEMM.
// ws: xn 8MB | q 8MB | k 8MB | vt 8MB | att 8MB | wt 16MB  (56MB)
// ---------------------------------------------------------------------------
extern "C" void kernel_launch(void* const* d_in, const int* in_sizes, int n_in,
                              void* d_out, int out_size, void* d_ws, size_t ws_size,
                              hipStream_t stream) {
  const float* x    = (const float*)d_in[0];
  const float* ln_g = (const float*)d_in[1];
  const float* ln_b = (const float*)d_in[2];
  const float* Wq   = (const float*)d_in[3];
  const float* bq   = (const float*)d_in[4];
  const float* Wk   = (const float*)d_in[5];
  const float* bk   = (const float*)d_in[6];
  const float* Wv   = (const float*)d_in[7];
  const float* bv   = (const float*)d_in[8];
  const float* Wo   = (const float*)d_in[9];
  const float* bo   = (const float*)d_in[10];
  float* out = (float*)d_out;

  ushort* ws  = (ushort*)d_ws;
  ushort* xn  = ws;
  ushort* qb  = xn + NE;
  ushort* kb  = qb + NE;
  ushort* vt  = kb + NE;
  ushort* ab  = vt + NE;
  ushort* wt  = ab + NE;               // 4 x [1024][1024] bf16
  ushort* wot = wt + (size_t)3 * DD * DD;

  prep<<<NROWS + 1024, 256, 0, stream>>>(x, ln_g, ln_b, xn, Wq, Wk, Wv, Wo, wt);

  gemm_qkv<<<dim3(NROWS / 128, 24), 256, 0, stream>>>(xn, wt, bq, bk, bv,
                                                      qb, kb, vt);

  attn_mfma<<<BB * HH * (SS / 64), 256, 0, stream>>>(qb, kb, vt, ab);

  gemm_o<<<dim3(NROWS / 128, DD / 64), 256, 0, stream>>>(ab, wot, bo, x, out);
}

// Round 13
// 102.284 us; speedup vs baseline: 1.0616x; 1.0069x over previous
//
#include <hip/hip_runtime.h>
#include <math.h>

// Problem constants: B=2, S=2048, D=1024, H=16, DQ=64
#define BB 2
#define SS 2048
#define DD 1024
#define HH 16
#define DQK 64
#define NROWS (BB * SS)
#define NE ((size_t)BB * SS * DD)   // 4,194,304

using short8 = __attribute__((ext_vector_type(8))) short;
using f32x4  = __attribute__((ext_vector_type(4))) float;

__device__ __forceinline__ ushort f2bf(float f) {
  union { float f; unsigned u; } c; c.f = f;
  return (ushort)((c.u + 0x7fffu + ((c.u >> 16) & 1u)) >> 16);
}

__device__ __forceinline__ unsigned cvt_pk_bf16(float lo, float hi) {
  unsigned r;
  asm("v_cvt_pk_bf16_f32 %0, %1, %2" : "=v"(r) : "v"(lo), "v"(hi));
  return r;
}

__device__ __forceinline__ f32x4 mfma16(short8 a, short8 b, f32x4 c) {
  return __builtin_amdgcn_mfma_f32_16x16x32_bf16(a, b, c, 0, 0, 0);
}

__device__ __forceinline__ float fmax3(float a, float b, float c) {
  return fmaxf(fmaxf(a, b), c);   // clang fuses to v_max3_f32
}

typedef __attribute__((address_space(1))) const unsigned gas_u32;
typedef __attribute__((address_space(3))) unsigned las_u32;
__device__ __forceinline__ void gload_lds16(const void* g, void* l) {
  __builtin_amdgcn_global_load_lds((gas_u32*)g, (las_u32*)l, 16, 0, 0);
}

// ---------------------------------------------------------------------------
// Fused prepass: blocks [0,4096) do LayerNorm->bf16 (one row each);
// blocks [4096,5120) transpose+cast the 4 weight matrices to Wt[N][K] bf16.
// ---------------------------------------------------------------------------
__global__ __launch_bounds__(256) void prep(const float* __restrict__ x,
                                            const float* __restrict__ g,
                                            const float* __restrict__ bta,
                                            ushort* __restrict__ xn,
                                            const float* __restrict__ Wq,
                                            const float* __restrict__ Wk,
                                            const float* __restrict__ Wv,
                                            const float* __restrict__ Wo,
                                            ushort* __restrict__ wt) {
  __shared__ float tile[64][65];
  const int t = threadIdx.x;
  if (blockIdx.x < NROWS) {
    const int row = blockIdx.x;
    float4 v = ((const float4*)(x + (size_t)row * DD))[t];
    float s  = v.x + v.y + v.z + v.w;
    float ss = v.x * v.x + v.y * v.y + v.z * v.z + v.w * v.w;
#pragma unroll
    for (int off = 32; off > 0; off >>= 1) {
      s  += __shfl_xor(s, off);
      ss += __shfl_xor(ss, off);
    }
    const int wid = t >> 6, lane = t & 63;
    if (lane == 0) { tile[0][wid] = s; tile[0][4 + wid] = ss; }
    __syncthreads();
    const float stot  = tile[0][0] + tile[0][1] + tile[0][2] + tile[0][3];
    const float sstot = tile[0][4] + tile[0][5] + tile[0][6] + tile[0][7];
    const float mu  = stot * (1.0f / DD);
    const float var = sstot * (1.0f / DD) - mu * mu;
    const float inv = rsqrtf(var + 1e-5f);
    const float4 g4 = ((const float4*)g)[t];
    const float4 b4 = ((const float4*)bta)[t];
    ushort4 o;
    o.x = f2bf((v.x - mu) * inv * g4.x + b4.x);
    o.y = f2bf((v.y - mu) * inv * g4.y + b4.y);
    o.z = f2bf((v.z - mu) * inv * g4.z + b4.z);
    o.w = f2bf((v.w - mu) * inv * g4.w + b4.w);
    ((ushort4*)(xn + (size_t)row * DD))[t] = o;
  } else {
    const int wb = blockIdx.x - NROWS;        // 0..1023
    const int z = wb >> 8;                    // matrix id
    const int k0 = (wb & 15) * 64, n0 = ((wb >> 4) & 15) * 64;
    const float* W = (z == 0) ? Wq : (z == 1) ? Wk : (z == 2) ? Wv : Wo;
    ushort* dst = wt + (size_t)z * DD * DD;
    const int tr = t >> 4, tc = (t & 15) * 4;
#pragma unroll
    for (int rr = 0; rr < 64; rr += 16) {
      float4 v = *(const float4*)(W + (size_t)(k0 + rr + tr) * DD + n0 + tc);
      tile[rr + tr][tc + 0] = v.x;
      tile[rr + tr][tc + 1] = v.y;
      tile[rr + tr][tc + 2] = v.z;
      tile[rr + tr][tc + 3] = v.w;
    }
    __syncthreads();
#pragma unroll
    for (int rr = 0; rr < 64; rr += 16) {
      const int n = rr + tr;
      ushort4 o;
      o.x = f2bf(tile[tc + 0][n]);
      o.y = f2bf(tile[tc + 1][n]);
      o.z = f2bf(tile[tc + 2][n]);
      o.w = f2bf(tile[tc + 3][n]);
      *(ushort4*)(dst + (size_t)(n0 + n) * DD + k0 + tc) = o;
    }
  }
}

// ---------------------------------------------------------------------------
// 128x128 GEMM core. 4 waves, BK=32, triple-buffered global_load_lds with
// counted vmcnt(4) + raw s_barrier. Read-side XOR (r16>>1)&3 (row bits 1-2).
// ---------------------------------------------------------------------------
#define GEMM_CORE(Ag, Bg)                                                     \
  f32x4 acc[4][4];                                                            \
  _Pragma("unroll")                                                           \
  for (int m = 0; m < 4; ++m)                                                 \
    _Pragma("unroll")                                                         \
    for (int n = 0; n < 4; ++n) acc[m][n] = (f32x4){0.f, 0.f, 0.f, 0.f};     \
  const int cs = ((t & 3) * 16) ^ (((t >> 3) & 3) * 16);                      \
  const int fsw = ((r16 >> 1) & 3) * 16;                                      \
  {                                                                           \
    GSTAGE(Ag, Bg, 0, 0);                                                     \
    GSTAGE(Ag, Bg, 1, 32);                                                    \
    int cb = 0;                                                               \
    for (int k0 = 0; k0 < DD; k0 += 32) {                                     \
      __builtin_amdgcn_sched_barrier(0);                                      \
      if (k0 + 32 < DD) {                                                     \
        asm volatile("s_waitcnt vmcnt(4)" ::: "memory");                      \
      } else {                                                                \
        asm volatile("s_waitcnt vmcnt(0)" ::: "memory");                      \
      }                                                                       \
      __builtin_amdgcn_s_barrier();                                           \
      __builtin_amdgcn_sched_barrier(0);                                      \
      if (k0 + 64 < DD) {                                                     \
        int nb = cb + 2; if (nb >= 3) nb -= 3;                                \
        GSTAGE(Ag, Bg, nb, k0 + 64);                                          \
      }                                                                       \
      const char* Ac = (const char*)&As[cb][0][0];                            \
      const char* Bc = (const char*)&Bs[cb][0][0];                            \
      short8 af[4], bf[4];                                                    \
      _Pragma("unroll")                                                       \
      for (int m = 0; m < 4; ++m)                                             \
        af[m] = *(const short8*)(Ac + (wr * 64 + m * 16 + r16) * 64 +         \
                                 ((g * 16) ^ fsw));                           \
      _Pragma("unroll")                                                       \
      for (int n = 0; n < 4; ++n)                                             \
        bf[n] = *(const short8*)(Bc + (wc * 64 + n * 16 + r16) * 64 +         \
                                 ((g * 16) ^ fsw));                           \
      _Pragma("unroll")                                                       \
      for (int m = 0; m < 4; ++m)                                             \
        _Pragma("unroll")                                                     \
        for (int n = 0; n < 4; ++n) acc[m][n] = mfma16(af[m], bf[n], acc[m][n]); \
      cb = (cb + 1 == 3) ? 0 : cb + 1;                                        \
    }                                                                         \
  }

#define GSTAGE(Ag, Bg, buf, k0)                                               \
  {                                                                           \
    _Pragma("unroll")                                                         \
    for (int i = 0; i < 2; ++i) {                                             \
      gload_lds16(Ag + (size_t)(row0 + i * 64 + (t >> 2)) * (DD * 2) +        \
                      (k0) * 2 + cs,                                          \
                  (char*)&As[buf][0][0] + i * 4096 + t * 16);                 \
      gload_lds16(Bg + (size_t)(col0 + i * 64 + (t >> 2)) * (DD * 2) +        \
                      (k0) * 2 + cs,                                          \
                  (char*)&Bs[buf][0][0] + i * 4096 + t * 16);                 \
    }                                                                         \
  }

// 128x64 GEMM core (for gemm_o): 512 blocks -> 2 blocks/CU, 2 waves/SIMD.
#define GEMM_CORE_O(Ag, Bg)                                                   \
  f32x4 acc[4][2];                                                            \
  _Pragma("unroll")                                                           \
  for (int m = 0; m < 4; ++m)                                                 \
    _Pragma("unroll")                                                         \
    for (int n = 0; n < 2; ++n) acc[m][n] = (f32x4){0.f, 0.f, 0.f, 0.f};     \
  const int cs = ((t & 3) * 16) ^ (((t >> 3) & 3) * 16);                      \
  const int fsw = ((r16 >> 1) & 3) * 16;                                      \
  {                                                                           \
    GSTAGE_O(Ag, Bg, 0, 0);                                                   \
    GSTAGE_O(Ag, Bg, 1, 32);                                                  \
    int cb = 0;                                                               \
    for (int k0 = 0; k0 < DD; k0 += 32) {                                     \
      __builtin_amdgcn_sched_barrier(0);                                      \
      if (k0 + 32 < DD) {                                                     \
        asm volatile("s_waitcnt vmcnt(3)" ::: "memory");                      \
      } else {                                                                \
        asm volatile("s_waitcnt vmcnt(0)" ::: "memory");                      \
      }                                                                       \
      __builtin_amdgcn_s_barrier();                                           \
      __builtin_amdgcn_sched_barrier(0);                                      \
      if (k0 + 64 < DD) {                                                     \
        int nb = cb + 2; if (nb >= 3) nb -= 3;                                \
        GSTAGE_O(Ag, Bg, nb, k0 + 64);                                        \
      }                                                                       \
      const char* Ac = (const char*)&As[cb][0][0];                            \
      const char* Bc = (const char*)&Bs[cb][0][0];                            \
      short8 af[4], bf[2];                                                    \
      _Pragma("unroll")                                                       \
      for (int m = 0; m < 4; ++m)                                             \
        af[m] = *(const short8*)(Ac + (wr * 64 + m * 16 + r16) * 64 +         \
                                 ((g * 16) ^ fsw));                           \
      _Pragma("unroll")                                                       \
      for (int n = 0; n < 2; ++n)                                             \
        bf[n] = *(const short8*)(Bc + (wc * 32 + n * 16 + r16) * 64 +         \
                                 ((g * 16) ^ fsw));                           \
      _Pragma("unroll")                                                       \
      for (int m = 0; m < 4; ++m)                                             \
        _Pragma("unroll")                                                     \
        for (int n = 0; n < 2; ++n) acc[m][n] = mfma16(af[m], bf[n], acc[m][n]); \
      cb = (cb + 1 == 3) ? 0 : cb + 1;                                        \
    }                                                                         \
  }

#define GSTAGE_O(Ag, Bg, buf, k0)                                             \
  {                                                                           \
    _Pragma("unroll")                                                         \
    for (int i = 0; i < 2; ++i)                                               \
      gload_lds16(Ag + (size_t)(row0 + i * 64 + (t >> 2)) * (DD * 2) +        \
                      (k0) * 2 + cs,                                          \
                  (char*)&As[buf][0][0] + i * 4096 + t * 16);                 \
    gload_lds16(Bg + (size_t)(col0 + (t >> 2)) * (DD * 2) + (k0) * 2 + cs,    \
                (char*)&Bs[buf][0][0] + t * 16);                              \
  }

// Fused QKV projection. Q output is PRE-SCALED by 1/sqrt(64)*log2(e).
__global__ __launch_bounds__(256, 3) void gemm_qkv(
    const ushort* __restrict__ A, const ushort* __restrict__ wt,
    const float* __restrict__ bq, const float* __restrict__ bk,
    const float* __restrict__ bv, ushort* __restrict__ qb,
    ushort* __restrict__ kb, ushort* __restrict__ vt) {
  __shared__ ushort As[3][128][32];
  __shared__ ushort Bs[3][128][32];
  const int t = threadIdx.x;
  const int lane = t & 63;
  const int w = t >> 6, wr = w >> 1, wc = w & 1;
  const int r16 = lane & 15, g = lane >> 4;
  const int row0 = blockIdx.x * 128;
  const int mat = blockIdx.y >> 3;
  const int col0 = (blockIdx.y & 7) * 128;
  const char* Ag = (const char*)A;
  const char* Bg = (const char*)(wt + (size_t)mat * DD * DD);
  const float* bias = (mat == 0) ? bq : (mat == 1) ? bk : bv;
  const float scl = (mat == 0) ? 0.125f * 1.44269504f : 1.0f;

  GEMM_CORE(Ag, Bg)

#pragma unroll
  for (int n = 0; n < 4; ++n) {
    const int c = col0 + wc * 64 + n * 16 + r16;
    const float bc = bias[c];
#pragma unroll
    for (int m = 0; m < 4; ++m) {
      const int rbase = row0 + wr * 64 + m * 16 + g * 4;
      if (mat < 2) {
        ushort* outb = (mat == 0) ? qb : kb;
#pragma unroll
        for (int e = 0; e < 4; ++e)
          outb[(size_t)(rbase + e) * DD + c] = f2bf((acc[m][n][e] + bc) * scl);
      } else {
        uint2 st;
        st.x = cvt_pk_bf16(acc[m][n][0] + bc, acc[m][n][1] + bc);
        st.y = cvt_pk_bf16(acc[m][n][2] + bc, acc[m][n][3] + bc);
        const size_t vrow = (size_t)((rbase >> 11) * HH + (c >> 6)) * DQK + (c & 63);
        *(uint2*)(vt + vrow * SS + (rbase & 2047)) = st;
      }
    }
  }
}

// Output projection: att @ Wo + bo + x -> fp32 out. 128x64 tiles, 512 blocks.
__global__ __launch_bounds__(256, 2) void gemm_o(
    const ushort* __restrict__ A, const ushort* __restrict__ Bt,
    const float* __restrict__ bias, const float* __restrict__ resid,
    float* __restrict__ outf) {
  __shared__ ushort As[3][128][32];
  __shared__ ushort Bs[3][64][32];
  const int t = threadIdx.x;
  const int lane = t & 63;
  const int w = t >> 6, wr = w >> 1, wc = w & 1;
  const int r16 = lane & 15, g = lane >> 4;
  const int row0 = blockIdx.x * 128;
  const int col0 = blockIdx.y * 64;
  const char* Ag = (const char*)A;
  const char* Bg = (const char*)Bt;

  GEMM_CORE_O(Ag, Bg)

#pragma unroll
  for (int n = 0; n < 2; ++n) {
    const int c = col0 + wc * 32 + n * 16 + r16;
    const float bc = bias[c];
#pragma unroll
    for (int m = 0; m < 4; ++m) {
      const int rbase = row0 + wr * 64 + m * 16 + g * 4;
#pragma unroll
      for (int e = 0; e < 4; ++e) {
        const size_t idx = (size_t)(rbase + e) * DD + c;
        outf[idx] = acc[m][n][e] + bc + resid[idx];
      }
    }
  }
}

// ---------------------------------------------------------------------------
// MFMA flash attention (causal). Round-10 pipeline structure, plus:
//  - pure-LPT descending dispatch: qb = 31 - (bid>>5) (longest blocks first)
//  - max tree via v_max3_f32 nesting (15 fmax -> 8 ops)
// rl is back to the VALU per-lane partial (round-11 form): the round-12
// ones-MFMA denominator produced NaNs (suspected codegen hazard with a third
// interleaved MFMA accumulator) and is reverted.
// Key relabeling keeps P in registers; swizzle bits {0,1,3}; 32KB dbuf.
// ---------------------------------------------------------------------------
__global__ __launch_bounds__(256, 4) void attn_mfma(const ushort* __restrict__ Q,
                                                    const ushort* __restrict__ K,
                                                    const ushort* __restrict__ Vt,
                                                    ushort* __restrict__ O) {
  __shared__ ushort Ks[2][64][64];  // [buf][key][d]  128B rows, swizzled
  __shared__ ushort Vs[2][64][64];  // [buf][dq][key] 128B rows, swizzled

  const int t = threadIdx.x, lane = t & 63, ww = t >> 6;
  const int r16 = lane & 15, g = lane >> 4;

  const int bid = blockIdx.x;                    // 1024 blocks
  const int xcd = bid & 7;
  const int bh = xcd * 4 + ((bid >> 3) & 3);     // 4 heads per XCD
  const int qb = 31 - (bid >> 5);                // pure LPT: heavy first
  const int b = bh >> 4, h = bh & 15;
  const size_t tokbase = (size_t)b * SS;
  const size_t hoff = (size_t)h * DQK;
  const int q0 = qb * 64 + ww * 16;
  const int nt = qb + 1;

  // --- staging bases (computed once; per-tile offset is affine) ---
  const int srow = t >> 3;                       // 0..31
  const int scol = (t & 7) * 16;
  const int Cs = scol ^ (((srow & 3) | ((srow >> 1) & 4)) << 4);
  const char* Kb = (const char*)(K + tokbase * DD + hoff);
  const char* Vb = (const char*)(Vt + (size_t)bh * DQK * SS);
  const char* kbase0 = Kb + (size_t)srow * (DD * 2) + Cs;
  const char* kbase1 = Kb + (size_t)(srow + 32) * (DD * 2) + Cs;
  const char* vbase0 = Vb + (size_t)srow * (SS * 2) + Cs;
  const char* vbase1 = Vb + (size_t)(srow + 32) * (SS * 2) + Cs;
  char* ksd = (char*)&Ks[0][0][0] + ww * 1024;   // wave-uniform LDS dests
  char* vsd = (char*)&Vs[0][0][0] + ww * 1024;

#define STAGE(BOFF, TILE)                                                     \
  {                                                                           \
    const size_t ko = (size_t)(TILE) << 17;  /* tile*64*DD*2 */               \
    const size_t vo = (size_t)(TILE) << 7;   /* tile*64*2   */                \
    gload_lds16(kbase0 + ko, ksd + (BOFF));                                   \
    gload_lds16(kbase1 + ko, ksd + (BOFF) + 4096);                            \
    gload_lds16(vbase0 + vo, vsd + (BOFF));                                   \
    gload_lds16(vbase1 + vo, vsd + (BOFF) + 4096);                            \
  }

  // --- precomputed LDS read offsets (registers; buffer picked via imm) ---
  const int sw = ((r16 & 3) | ((r16 >> 1) & 4)) << 4;  // V-read swz bits {0,1,3}
  const int rlo = (r16 & 3) + ((r16 >> 2) << 3);       // K-row permutation base
  int offk[4][2], offv[4][2];
#pragma unroll
  for (int t2 = 0; t2 < 4; ++t2) {
    const int kk = rlo + (t2 & 1) * 4 + (t2 >> 1) * 32;
    const int sk = ((kk & 3) | ((kk >> 1) & 4)) << 4;
    offk[t2][0] = kk * 128 + ((g * 16) ^ sk);
    offk[t2][1] = kk * 128 + ((64 + g * 16) ^ sk);
  }
#pragma unroll
  for (int dt = 0; dt < 4; ++dt) {
    offv[dt][0] = (dt * 16 + r16) * 128 + ((g * 16) ^ sw);
    offv[dt][1] = (dt * 16 + r16) * 128 + ((64 + g * 16) ^ sw);
  }
  const char* KsB = (const char*)&Ks[0][0][0];
  const char* VsB = (const char*)&Vs[0][0][0];

  // Q fragments (B-operand, pre-scaled into exp2 domain by gemm_qkv)
  const short8 qc0 = *(const short8*)(Q + (tokbase + q0 + r16) * DD + hoff + g * 8);
  const short8 qc1 = *(const short8*)(Q + (tokbase + q0 + r16) * DD + hoff + 32 + g * 8);

  f32x4 o[4];
#pragma unroll
  for (int dt = 0; dt < 4; ++dt) o[dt] = (f32x4){0.f, 0.f, 0.f, 0.f};
  float rm = -INFINITY, rl = 0.f;                // rl is a per-lane PARTIAL

#define COMPUTE(BOFF, DOMASK, TLOC)                                           \
  {                                                                           \
    f32x4 s4[4];                                                              \
    __builtin_amdgcn_s_setprio(1);                                            \
    _Pragma("unroll")                                                         \
    for (int t2 = 0; t2 < 4; ++t2) {                                          \
      const short8 k0 = *(const short8*)(KsB + (BOFF) + offk[t2][0]);         \
      const short8 k1 = *(const short8*)(KsB + (BOFF) + offk[t2][1]);         \
      f32x4 s = mfma16(k0, qc0, (f32x4){0.f, 0.f, 0.f, 0.f});                 \
      s4[t2] = mfma16(k1, qc1, s);                                            \
    }                                                                         \
    __builtin_amdgcn_s_setprio(0);                                            \
    if (DOMASK) {                                                             \
      const int thrl = q0 + r16 - g * 8 - (TLOC) * 64;                        \
      _Pragma("unroll")                                                       \
      for (int t2 = 0; t2 < 4; ++t2) {                                        \
        const int bb = (t2 & 1) * 4 + (t2 >> 1) * 32;                         \
        _Pragma("unroll")                                                     \
        for (int r = 0; r < 4; ++r)                                           \
          s4[t2][r] = (bb + r <= thrl) ? s4[t2][r] : -INFINITY;               \
      }                                                                       \
    }                                                                         \
    float m0 = fmax3(s4[0][0], s4[0][1], s4[0][2]);                           \
    float m1 = fmax3(s4[0][3], s4[1][0], s4[1][1]);                           \
    float m2 = fmax3(s4[1][2], s4[1][3], s4[2][0]);                           \
    float m3 = fmax3(s4[2][1], s4[2][2], s4[2][3]);                           \
    float m4 = fmax3(s4[3][0], s4[3][1], s4[3][2]);                           \
    float mx = fmaxf(fmax3(m0, m1, m2), fmax3(m3, m4, s4[3][3]));             \
    if (!__all(mx - rm <= 8.f)) {                                             \
      float mf = fmaxf(mx, __shfl_xor(mx, 16));                               \
      mf = fmaxf(mf, __shfl_xor(mf, 32));                                     \
      const float mn = fmaxf(rm, mf);                                         \
      const float sc = __builtin_amdgcn_exp2f(rm - mn);                       \
      rl *= sc;                                                               \
      _Pragma("unroll")                                                       \
      for (int dt = 0; dt < 4; ++dt) o[dt] *= sc;                             \
      rm = mn;                                                                \
    }                                                                         \
    union { unsigned u[4]; short8 s; } pbu[2];                                \
    _Pragma("unroll")                                                         \
    for (int t2 = 0; t2 < 4; ++t2) {                                          \
      const float p0 = __builtin_amdgcn_exp2f(s4[t2][0] - rm);                \
      const float p1 = __builtin_amdgcn_exp2f(s4[t2][1] - rm);                \
      const float p2 = __builtin_amdgcn_exp2f(s4[t2][2] - rm);                \
      const float p3 = __builtin_amdgcn_exp2f(s4[t2][3] - rm);                \
      rl += (p0 + p1) + (p2 + p3);                                            \
      pbu[t2 >> 1].u[(t2 & 1) * 2 + 0] = cvt_pk_bf16(p0, p1);                 \
      pbu[t2 >> 1].u[(t2 & 1) * 2 + 1] = cvt_pk_bf16(p2, p3);                 \
    }                                                                         \
    __builtin_amdgcn_s_setprio(1);                                            \
    _Pragma("unroll")                                                         \
    for (int kc = 0; kc < 2; ++kc)                                            \
      _Pragma("unroll")                                                       \
      for (int dt = 0; dt < 4; ++dt) {                                        \
        const short8 vf = *(const short8*)(VsB + (BOFF) + offv[dt][kc]);      \
        o[dt] = mfma16(vf, pbu[kc].s, o[dt]);                                 \
      }                                                                       \
    __builtin_amdgcn_s_setprio(0);                                            \
  }

#define WAITBAR                                                               \
  __builtin_amdgcn_sched_barrier(0);                                          \
  asm volatile("s_waitcnt vmcnt(0)" ::: "memory");                            \
  __builtin_amdgcn_s_barrier();                                               \
  __builtin_amdgcn_sched_barrier(0);

  STAGE(0, 0);
  int tt = 0;
#pragma unroll 1
  for (; tt + 2 <= nt; tt += 2) {
    // even tile tt (buf0) -- provably non-diagonal (tt <= nt-2)
    WAITBAR;                                     // drains S(tt) only
    STAGE(8192, tt + 1);                         // -> buf1
    COMPUTE(0, false, 0);
    // odd tile tt+1 (buf1) -- diagonal iff tt+2 == nt
    WAITBAR;                                     // drains S(tt+1) only
    {
      int pj = tt + 2; if (pj >= nt) pj = 0;     // clamped prefetch (unused if wrap)
      STAGE(0, pj);                              // -> buf0
    }
    COMPUTE(8192, (tt + 2 == nt), (tt + 1));
  }
  if (tt < nt) {                                 // odd-nt tail: diagonal tile
    WAITBAR;
    COMPUTE(0, true, tt);
  }
#undef STAGE
#undef COMPUTE
#undef WAITBAR

  // --- cross-lane l-reduction, once ---
  rl += __shfl_xor(rl, 16);
  rl += __shfl_xor(rl, 32);
  const float inv = 1.0f / rl;
#pragma unroll
  for (int dt = 0; dt < 4; ++dt) {
    uint2 st;
    st.x = cvt_pk_bf16(o[dt][0] * inv, o[dt][1] * inv);
    st.y = cvt_pk_bf16(o[dt][2] * inv, o[dt][3] * inv);
    *(uint2*)(O + (tokbase + q0 + r16) * DD + hoff + dt * 16 + g * 4) = st;
  }
}

// ---------------------------------------------------------------------------
// Launch: prep (LN + wtrans fused) -> fused QKV GEMM -> attn -> O-GEMM.
// ws: xn 8MB | q 8MB | k 8MB | vt 8MB | att 8MB | wt 16MB  (56MB)
// ---------------------------------------------------------------------------
extern "C" void kernel_launch(void* const* d_in, const int* in_sizes, int n_in,
                              void* d_out, int out_size, void* d_ws, size_t ws_size,
                              hipStream_t stream) {
  const float* x    = (const float*)d_in[0];
  const float* ln_g = (const float*)d_in[1];
  const float* ln_b = (const float*)d_in[2];
  const float* Wq   = (const float*)d_in[3];
  const float* bq   = (const float*)d_in[4];
  const float* Wk   = (const float*)d_in[5];
  const float* bk   = (const float*)d_in[6];
  const float* Wv   = (const float*)d_in[7];
  const float* bv   = (const float*)d_in[8];
  const float* Wo   = (const float*)d_in[9];
  const float* bo   = (const float*)d_in[10];
  float* out = (float*)d_out;

  ushort* ws  = (ushort*)d_ws;
  ushort* xn  = ws;
  ushort* qb  = xn + NE;
  ushort* kb  = qb + NE;
  ushort* vt  = kb + NE;
  ushort* ab  = vt + NE;
  ushort* wt  = ab + NE;               // 4 x [1024][1024] bf16
  ushort* wot = wt + (size_t)3 * DD * DD;

  prep<<<NROWS + 1024, 256, 0, stream>>>(x, ln_g, ln_b, xn, Wq, Wk, Wv, Wo, wt);

  gemm_qkv<<<dim3(NROWS / 128, 24), 256, 0, stream>>>(xn, wt, bq, bk, bv,
                                                      qb, kb, vt);

  attn_mfma<<<BB * HH * (SS / 64), 256, 0, stream>>>(qb, kb, vt, ab);

  gemm_o<<<dim3(NROWS / 128, DD / 64), 256, 0, stream>>>(ab, wot, bo, x, out);
}

// Round 14
// 100.716 us; speedup vs baseline: 1.0781x; 1.0156x over previous
//
#include <hip/hip_runtime.h>
#include <math.h>

// Problem constants: B=2, S=2048, D=1024, H=16, DQ=64
#define BB 2
#define SS 2048
#define DD 1024
#define HH 16
#define DQK 64
#define NROWS (BB * SS)
#define NE ((size_t)BB * SS * DD)   // 4,194,304

using short8 = __attribute__((ext_vector_type(8))) short;
using f32x4  = __attribute__((ext_vector_type(4))) float;

__device__ __forceinline__ ushort f2bf(float f) {
  union { float f; unsigned u; } c; c.f = f;
  return (ushort)((c.u + 0x7fffu + ((c.u >> 16) & 1u)) >> 16);
}

__device__ __forceinline__ unsigned cvt_pk_bf16(float lo, float hi) {
  unsigned r;
  asm("v_cvt_pk_bf16_f32 %0, %1, %2" : "=v"(r) : "v"(lo), "v"(hi));
  return r;
}

__device__ __forceinline__ f32x4 mfma16(short8 a, short8 b, f32x4 c) {
  return __builtin_amdgcn_mfma_f32_16x16x32_bf16(a, b, c, 0, 0, 0);
}

__device__ __forceinline__ float fmax3(float a, float b, float c) {
  return fmaxf(fmaxf(a, b), c);   // clang fuses to v_max3_f32
}

typedef __attribute__((address_space(1))) const unsigned gas_u32;
typedef __attribute__((address_space(3))) unsigned las_u32;
__device__ __forceinline__ void gload_lds16(const void* g, void* l) {
  __builtin_amdgcn_global_load_lds((gas_u32*)g, (las_u32*)l, 16, 0, 0);
}

// ---------------------------------------------------------------------------
// Fused prepass.
// Blocks [0,1024): LayerNorm->bf16, ONE WAVE PER ROW (4 rows/block): no LDS,
// no __syncthreads; 64-lane shfl reduction; 4x float4 per lane.
// Blocks [1024,2048): transpose+cast the 4 weight matrices to Wt[N][K] bf16.
// ---------------------------------------------------------------------------
__global__ __launch_bounds__(256) void prep(const float* __restrict__ x,
                                            const float* __restrict__ g,
                                            const float* __restrict__ bta,
                                            ushort* __restrict__ xn,
                                            const float* __restrict__ Wq,
                                            const float* __restrict__ Wk,
                                            const float* __restrict__ Wv,
                                            const float* __restrict__ Wo,
                                            ushort* __restrict__ wt) {
  const int t = threadIdx.x;
  if (blockIdx.x < NROWS / 4) {
    const int lane = t & 63, wid = t >> 6;
    const int row = blockIdx.x * 4 + wid;
    const float4* xr = (const float4*)(x + (size_t)row * DD);
    float4 v[4];
    float s = 0.f, ss = 0.f;
#pragma unroll
    for (int c = 0; c < 4; ++c) {
      v[c] = xr[c * 64 + lane];
      s  += (v[c].x + v[c].y) + (v[c].z + v[c].w);
      ss += (v[c].x * v[c].x + v[c].y * v[c].y) +
            (v[c].z * v[c].z + v[c].w * v[c].w);
    }
#pragma unroll
    for (int off = 32; off > 0; off >>= 1) {
      s  += __shfl_xor(s, off);
      ss += __shfl_xor(ss, off);
    }
    const float mu  = s * (1.0f / DD);
    const float var = ss * (1.0f / DD) - mu * mu;
    const float inv = rsqrtf(var + 1e-5f);
    ushort4* xo = (ushort4*)(xn + (size_t)row * DD);
#pragma unroll
    for (int c = 0; c < 4; ++c) {
      const float4 g4 = ((const float4*)g)[c * 64 + lane];
      const float4 b4 = ((const float4*)bta)[c * 64 + lane];
      ushort4 o;
      o.x = f2bf((v[c].x - mu) * inv * g4.x + b4.x);
      o.y = f2bf((v[c].y - mu) * inv * g4.y + b4.y);
      o.z = f2bf((v[c].z - mu) * inv * g4.z + b4.z);
      o.w = f2bf((v[c].w - mu) * inv * g4.w + b4.w);
      xo[c * 64 + lane] = o;
    }
  } else {
    __shared__ float tile[64][65];
    const int wb = blockIdx.x - NROWS / 4;    // 0..1023
    const int z = wb >> 8;                    // matrix id
    const int k0 = (wb & 15) * 64, n0 = ((wb >> 4) & 15) * 64;
    const float* W = (z == 0) ? Wq : (z == 1) ? Wk : (z == 2) ? Wv : Wo;
    ushort* dst = wt + (size_t)z * DD * DD;
    const int tr = t >> 4, tc = (t & 15) * 4;
#pragma unroll
    for (int rr = 0; rr < 64; rr += 16) {
      float4 v = *(const float4*)(W + (size_t)(k0 + rr + tr) * DD + n0 + tc);
      tile[rr + tr][tc + 0] = v.x;
      tile[rr + tr][tc + 1] = v.y;
      tile[rr + tr][tc + 2] = v.z;
      tile[rr + tr][tc + 3] = v.w;
    }
    __syncthreads();
#pragma unroll
    for (int rr = 0; rr < 64; rr += 16) {
      const int n = rr + tr;
      ushort4 o;
      o.x = f2bf(tile[tc + 0][n]);
      o.y = f2bf(tile[tc + 1][n]);
      o.z = f2bf(tile[tc + 2][n]);
      o.w = f2bf(tile[tc + 3][n]);
      *(ushort4*)(dst + (size_t)(n0 + n) * DD + k0 + tc) = o;
    }
  }
}

// ---------------------------------------------------------------------------
// 128x128 GEMM core. 4 waves, BK=32, triple-buffered global_load_lds with
// counted vmcnt(4) + raw s_barrier. Read-side XOR (r16>>1)&3 (row bits 1-2).
// ---------------------------------------------------------------------------
#define GEMM_CORE(Ag, Bg)                                                     \
  f32x4 acc[4][4];                                                            \
  _Pragma("unroll")                                                           \
  for (int m = 0; m < 4; ++m)                                                 \
    _Pragma("unroll")                                                         \
    for (int n = 0; n < 4; ++n) acc[m][n] = (f32x4){0.f, 0.f, 0.f, 0.f};     \
  const int cs = ((t & 3) * 16) ^ (((t >> 3) & 3) * 16);                      \
  const int fsw = ((r16 >> 1) & 3) * 16;                                      \
  {                                                                           \
    GSTAGE(Ag, Bg, 0, 0);                                                     \
    GSTAGE(Ag, Bg, 1, 32);                                                    \
    int cb = 0;                                                               \
    for (int k0 = 0; k0 < DD; k0 += 32) {                                     \
      __builtin_amdgcn_sched_barrier(0);                                      \
      if (k0 + 32 < DD) {                                                     \
        asm volatile("s_waitcnt vmcnt(4)" ::: "memory");                      \
      } else {                                                                \
        asm volatile("s_waitcnt vmcnt(0)" ::: "memory");                      \
      }                                                                       \
      __builtin_amdgcn_s_barrier();                                           \
      __builtin_amdgcn_sched_barrier(0);                                      \
      if (k0 + 64 < DD) {                                                     \
        int nb = cb + 2; if (nb >= 3) nb -= 3;                                \
        GSTAGE(Ag, Bg, nb, k0 + 64);                                          \
      }                                                                       \
      const char* Ac = (const char*)&As[cb][0][0];                            \
      const char* Bc = (const char*)&Bs[cb][0][0];                            \
      short8 af[4], bf[4];                                                    \
      _Pragma("unroll")                                                       \
      for (int m = 0; m < 4; ++m)                                             \
        af[m] = *(const short8*)(Ac + (wr * 64 + m * 16 + r16) * 64 +         \
                                 ((g * 16) ^ fsw));                           \
      _Pragma("unroll")                                                       \
      for (int n = 0; n < 4; ++n)                                             \
        bf[n] = *(const short8*)(Bc + (wc * 64 + n * 16 + r16) * 64 +         \
                                 ((g * 16) ^ fsw));                           \
      _Pragma("unroll")                                                       \
      for (int m = 0; m < 4; ++m)                                             \
        _Pragma("unroll")                                                     \
        for (int n = 0; n < 4; ++n) acc[m][n] = mfma16(af[m], bf[n], acc[m][n]); \
      cb = (cb + 1 == 3) ? 0 : cb + 1;                                        \
    }                                                                         \
  }

#define GSTAGE(Ag, Bg, buf, k0)                                               \
  {                                                                           \
    _Pragma("unroll")                                                         \
    for (int i = 0; i < 2; ++i) {                                             \
      gload_lds16(Ag + (size_t)(row0 + i * 64 + (t >> 2)) * (DD * 2) +        \
                      (k0) * 2 + cs,                                          \
                  (char*)&As[buf][0][0] + i * 4096 + t * 16);                 \
      gload_lds16(Bg + (size_t)(col0 + i * 64 + (t >> 2)) * (DD * 2) +        \
                      (k0) * 2 + cs,                                          \
                  (char*)&Bs[buf][0][0] + i * 4096 + t * 16);                 \
    }                                                                         \
  }

// 128x64 GEMM core (for gemm_o): 512 blocks -> 2 blocks/CU, 2 waves/SIMD.
#define GEMM_CORE_O(Ag, Bg)                                                   \
  f32x4 acc[4][2];                                                            \
  _Pragma("unroll")                                                           \
  for (int m = 0; m < 4; ++m)                                                 \
    _Pragma("unroll")                                                         \
    for (int n = 0; n < 2; ++n) acc[m][n] = (f32x4){0.f, 0.f, 0.f, 0.f};     \
  const int cs = ((t & 3) * 16) ^ (((t >> 3) & 3) * 16);                      \
  const int fsw = ((r16 >> 1) & 3) * 16;                                      \
  {                                                                           \
    GSTAGE_O(Ag, Bg, 0, 0);                                                   \
    GSTAGE_O(Ag, Bg, 1, 32);                                                  \
    int cb = 0;                                                               \
    for (int k0 = 0; k0 < DD; k0 += 32) {                                     \
      __builtin_amdgcn_sched_barrier(0);                                      \
      if (k0 + 32 < DD) {                                                     \
        asm volatile("s_waitcnt vmcnt(3)" ::: "memory");                      \
      } else {                                                                \
        asm volatile("s_waitcnt vmcnt(0)" ::: "memory");                      \
      }                                                                       \
      __builtin_amdgcn_s_barrier();                                           \
      __builtin_amdgcn_sched_barrier(0);                                      \
      if (k0 + 64 < DD) {                                                     \
        int nb = cb + 2; if (nb >= 3) nb -= 3;                                \
        GSTAGE_O(Ag, Bg, nb, k0 + 64);                                        \
      }                                                                       \
      const char* Ac = (const char*)&As[cb][0][0];                            \
      const char* Bc = (const char*)&Bs[cb][0][0];                            \
      short8 af[4], bf[2];                                                    \
      _Pragma("unroll")                                                       \
      for (int m = 0; m < 4; ++m)                                             \
        af[m] = *(const short8*)(Ac + (wr * 64 + m * 16 + r16) * 64 +         \
                                 ((g * 16) ^ fsw));                           \
      _Pragma("unroll")                                                       \
      for (int n = 0; n < 2; ++n)                                             \
        bf[n] = *(const short8*)(Bc + (wc * 32 + n * 16 + r16) * 64 +         \
                                 ((g * 16) ^ fsw));                           \
      _Pragma("unroll")                                                       \
      for (int m = 0; m < 4; ++m)                                             \
        _Pragma("unroll")                                                     \
        for (int n = 0; n < 2; ++n) acc[m][n] = mfma16(af[m], bf[n], acc[m][n]); \
      cb = (cb + 1 == 3) ? 0 : cb + 1;                                        \
    }                                                                         \
  }

#define GSTAGE_O(Ag, Bg, buf, k0)                                             \
  {                                                                           \
    _Pragma("unroll")                                                         \
    for (int i = 0; i < 2; ++i)                                               \
      gload_lds16(Ag + (size_t)(row0 + i * 64 + (t >> 2)) * (DD * 2) +        \
                      (k0) * 2 + cs,                                          \
                  (char*)&As[buf][0][0] + i * 4096 + t * 16);                 \
    gload_lds16(Bg + (size_t)(col0 + (t >> 2)) * (DD * 2) + (k0) * 2 + cs,    \
                (char*)&Bs[buf][0][0] + t * 16);                              \
  }

// Fused QKV projection. Q output is PRE-SCALED by 1/sqrt(64)*log2(e).
__global__ __launch_bounds__(256, 3) void gemm_qkv(
    const ushort* __restrict__ A, const ushort* __restrict__ wt,
    const float* __restrict__ bq, const float* __restrict__ bk,
    const float* __restrict__ bv, ushort* __restrict__ qb,
    ushort* __restrict__ kb, ushort* __restrict__ vt) {
  __shared__ ushort As[3][128][32];
  __shared__ ushort Bs[3][128][32];
  const int t = threadIdx.x;
  const int lane = t & 63;
  const int w = t >> 6, wr = w >> 1, wc = w & 1;
  const int r16 = lane & 15, g = lane >> 4;
  const int row0 = blockIdx.x * 128;
  const int mat = blockIdx.y >> 3;
  const int col0 = (blockIdx.y & 7) * 128;
  const char* Ag = (const char*)A;
  const char* Bg = (const char*)(wt + (size_t)mat * DD * DD);
  const float* bias = (mat == 0) ? bq : (mat == 1) ? bk : bv;
  const float scl = (mat == 0) ? 0.125f * 1.44269504f : 1.0f;

  GEMM_CORE(Ag, Bg)

#pragma unroll
  for (int n = 0; n < 4; ++n) {
    const int c = col0 + wc * 64 + n * 16 + r16;
    const float bc = bias[c];
#pragma unroll
    for (int m = 0; m < 4; ++m) {
      const int rbase = row0 + wr * 64 + m * 16 + g * 4;
      if (mat < 2) {
        ushort* outb = (mat == 0) ? qb : kb;
#pragma unroll
        for (int e = 0; e < 4; ++e)
          outb[(size_t)(rbase + e) * DD + c] = f2bf((acc[m][n][e] + bc) * scl);
      } else {
        uint2 st;
        st.x = cvt_pk_bf16(acc[m][n][0] + bc, acc[m][n][1] + bc);
        st.y = cvt_pk_bf16(acc[m][n][2] + bc, acc[m][n][3] + bc);
        const size_t vrow = (size_t)((rbase >> 11) * HH + (c >> 6)) * DQK + (c & 63);
        *(uint2*)(vt + vrow * SS + (rbase & 2047)) = st;
      }
    }
  }
}

// Output projection: att @ Wo + bo + x -> fp32 out. 128x64 tiles, 512 blocks.
__global__ __launch_bounds__(256, 2) void gemm_o(
    const ushort* __restrict__ A, const ushort* __restrict__ Bt,
    const float* __restrict__ bias, const float* __restrict__ resid,
    float* __restrict__ outf) {
  __shared__ ushort As[3][128][32];
  __shared__ ushort Bs[3][64][32];
  const int t = threadIdx.x;
  const int lane = t & 63;
  const int w = t >> 6, wr = w >> 1, wc = w & 1;
  const int r16 = lane & 15, g = lane >> 4;
  const int row0 = blockIdx.x * 128;
  const int col0 = blockIdx.y * 64;
  const char* Ag = (const char*)A;
  const char* Bg = (const char*)Bt;

  GEMM_CORE_O(Ag, Bg)

#pragma unroll
  for (int n = 0; n < 2; ++n) {
    const int c = col0 + wc * 32 + n * 16 + r16;
    const float bc = bias[c];
#pragma unroll
    for (int m = 0; m < 4; ++m) {
      const int rbase = row0 + wr * 64 + m * 16 + g * 4;
#pragma unroll
      for (int e = 0; e < 4; ++e) {
        const size_t idx = (size_t)(rbase + e) * DD + c;
        outf[idx] = acc[m][n][e] + bc + resid[idx];
      }
    }
  }
}

// ---------------------------------------------------------------------------
// MFMA flash attention (causal). Round-13 structure unchanged:
//  - pure-LPT descending dispatch: qb = 31 - (bid>>5)
//  - max tree via v_max3_f32 nesting
//  - per-lane partial rl, cross-lane reduce once in epilogue
//  - key relabeling keeps P in registers; swizzle bits {0,1,3}; 32KB dbuf
// ---------------------------------------------------------------------------
__global__ __launch_bounds__(256, 4) void attn_mfma(const ushort* __restrict__ Q,
                                                    const ushort* __restrict__ K,
                                                    const ushort* __restrict__ Vt,
                                                    ushort* __restrict__ O) {
  __shared__ ushort Ks[2][64][64];  // [buf][key][d]  128B rows, swizzled
  __shared__ ushort Vs[2][64][64];  // [buf][dq][key] 128B rows, swizzled

  const int t = threadIdx.x, lane = t & 63, ww = t >> 6;
  const int r16 = lane & 15, g = lane >> 4;

  const int bid = blockIdx.x;                    // 1024 blocks
  const int xcd = bid & 7;
  const int bh = xcd * 4 + ((bid >> 3) & 3);     // 4 heads per XCD
  const int qb = 31 - (bid >> 5);                // pure LPT: heavy first
  const int b = bh >> 4, h = bh & 15;
  const size_t tokbase = (size_t)b * SS;
  const size_t hoff = (size_t)h * DQK;
  const int q0 = qb * 64 + ww * 16;
  const int nt = qb + 1;

  // --- staging bases (computed once; per-tile offset is affine) ---
  const int srow = t >> 3;                       // 0..31
  const int scol = (t & 7) * 16;
  const int Cs = scol ^ (((srow & 3) | ((srow >> 1) & 4)) << 4);
  const char* Kb = (const char*)(K + tokbase * DD + hoff);
  const char* Vb = (const char*)(Vt + (size_t)bh * DQK * SS);
  const char* kbase0 = Kb + (size_t)srow * (DD * 2) + Cs;
  const char* kbase1 = Kb + (size_t)(srow + 32) * (DD * 2) + Cs;
  const char* vbase0 = Vb + (size_t)srow * (SS * 2) + Cs;
  const char* vbase1 = Vb + (size_t)(srow + 32) * (SS * 2) + Cs;
  char* ksd = (char*)&Ks[0][0][0] + ww * 1024;   // wave-uniform LDS dests
  char* vsd = (char*)&Vs[0][0][0] + ww * 1024;

#define STAGE(BOFF, TILE)                                                     \
  {                                                                           \
    const size_t ko = (size_t)(TILE) << 17;  /* tile*64*DD*2 */               \
    const size_t vo = (size_t)(TILE) << 7;   /* tile*64*2   */                \
    gload_lds16(kbase0 + ko, ksd + (BOFF));                                   \
    gload_lds16(kbase1 + ko, ksd + (BOFF) + 4096);                            \
    gload_lds16(vbase0 + vo, vsd + (BOFF));                                   \
    gload_lds16(vbase1 + vo, vsd + (BOFF) + 4096);                            \
  }

  // --- precomputed LDS read offsets (registers; buffer picked via imm) ---
  const int sw = ((r16 & 3) | ((r16 >> 1) & 4)) << 4;  // V-read swz bits {0,1,3}
  const int rlo = (r16 & 3) + ((r16 >> 2) << 3);       // K-row permutation base
  int offk[4][2], offv[4][2];
#pragma unroll
  for (int t2 = 0; t2 < 4; ++t2) {
    const int kk = rlo + (t2 & 1) * 4 + (t2 >> 1) * 32;
    const int sk = ((kk & 3) | ((kk >> 1) & 4)) << 4;
    offk[t2][0] = kk * 128 + ((g * 16) ^ sk);
    offk[t2][1] = kk * 128 + ((64 + g * 16) ^ sk);
  }
#pragma unroll
  for (int dt = 0; dt < 4; ++dt) {
    offv[dt][0] = (dt * 16 + r16) * 128 + ((g * 16) ^ sw);
    offv[dt][1] = (dt * 16 + r16) * 128 + ((64 + g * 16) ^ sw);
  }
  const char* KsB = (const char*)&Ks[0][0][0];
  const char* VsB = (const char*)&Vs[0][0][0];

  // Q fragments (B-operand, pre-scaled into exp2 domain by gemm_qkv)
  const short8 qc0 = *(const short8*)(Q + (tokbase + q0 + r16) * DD + hoff + g * 8);
  const short8 qc1 = *(const short8*)(Q + (tokbase + q0 + r16) * DD + hoff + 32 + g * 8);

  f32x4 o[4];
#pragma unroll
  for (int dt = 0; dt < 4; ++dt) o[dt] = (f32x4){0.f, 0.f, 0.f, 0.f};
  float rm = -INFINITY, rl = 0.f;                // rl is a per-lane PARTIAL

#define COMPUTE(BOFF, DOMASK, TLOC)                                           \
  {                                                                           \
    f32x4 s4[4];                                                              \
    __builtin_amdgcn_s_setprio(1);                                            \
    _Pragma("unroll")                                                         \
    for (int t2 = 0; t2 < 4; ++t2) {                                          \
      const short8 k0 = *(const short8*)(KsB + (BOFF) + offk[t2][0]);         \
      const short8 k1 = *(const short8*)(KsB + (BOFF) + offk[t2][1]);         \
      f32x4 s = mfma16(k0, qc0, (f32x4){0.f, 0.f, 0.f, 0.f});                 \
      s4[t2] = mfma16(k1, qc1, s);                                            \
    }                                                                         \
    __builtin_amdgcn_s_setprio(0);                                            \
    if (DOMASK) {                                                             \
      const int thrl = q0 + r16 - g * 8 - (TLOC) * 64;                        \
      _Pragma("unroll")                                                       \
      for (int t2 = 0; t2 < 4; ++t2) {                                        \
        const int bb = (t2 & 1) * 4 + (t2 >> 1) * 32;                         \
        _Pragma("unroll")                                                     \
        for (int r = 0; r < 4; ++r)                                           \
          s4[t2][r] = (bb + r <= thrl) ? s4[t2][r] : -INFINITY;               \
      }                                                                       \
    }                                                                         \
    float m0 = fmax3(s4[0][0], s4[0][1], s4[0][2]);                           \
    float m1 = fmax3(s4[0][3], s4[1][0], s4[1][1]);                           \
    float m2 = fmax3(s4[1][2], s4[1][3], s4[2][0]);                           \
    float m3 = fmax3(s4[2][1], s4[2][2], s4[2][3]);                           \
    float m4 = fmax3(s4[3][0], s4[3][1], s4[3][2]);                           \
    float mx = fmaxf(fmax3(m0, m1, m2), fmax3(m3, m4, s4[3][3]));             \
    if (!__all(mx - rm <= 8.f)) {                                             \
      float mf = fmaxf(mx, __shfl_xor(mx, 16));                               \
      mf = fmaxf(mf, __shfl_xor(mf, 32));                                     \
      const float mn = fmaxf(rm, mf);                                         \
      const float sc = __builtin_amdgcn_exp2f(rm - mn);                       \
      rl *= sc;                                                               \
      _Pragma("unroll")                                                       \
      for (int dt = 0; dt < 4; ++dt) o[dt] *= sc;                             \
      rm = mn;                                                                \
    }                                                                         \
    union { unsigned u[4]; short8 s; } pbu[2];                                \
    _Pragma("unroll")                                                         \
    for (int t2 = 0; t2 < 4; ++t2) {                                          \
      const float p0 = __builtin_amdgcn_exp2f(s4[t2][0] - rm);                \
      const float p1 = __builtin_amdgcn_exp2f(s4[t2][1] - rm);                \
      const float p2 = __builtin_amdgcn_exp2f(s4[t2][2] - rm);                \
      const float p3 = __builtin_amdgcn_exp2f(s4[t2][3] - rm);                \
      rl += (p0 + p1) + (p2 + p3);                                            \
      pbu[t2 >> 1].u[(t2 & 1) * 2 + 0] = cvt_pk_bf16(p0, p1);                 \
      pbu[t2 >> 1].u[(t2 & 1) * 2 + 1] = cvt_pk_bf16(p2, p3);                 \
    }                                                                         \
    __builtin_amdgcn_s_setprio(1);                                            \
    _Pragma("unroll")                                                         \
    for (int kc = 0; kc < 2; ++kc)                                            \
      _Pragma("unroll")                                                       \
      for (int dt = 0; dt < 4; ++dt) {                                        \
        const short8 vf = *(const short8*)(VsB + (BOFF) + offv[dt][kc]);      \
        o[dt] = mfma16(vf, pbu[kc].s, o[dt]);                                 \
      }                                                                       \
    __builtin_amdgcn_s_setprio(0);                                            \
  }

#define WAITBAR                                                               \
  __builtin_amdgcn_sched_barrier(0);                                          \
  asm volatile("s_waitcnt vmcnt(0)" ::: "memory");                            \
  __builtin_amdgcn_s_barrier();                                               \
  __builtin_amdgcn_sched_barrier(0);

  STAGE(0, 0);
  int tt = 0;
#pragma unroll 1
  for (; tt + 2 <= nt; tt += 2) {
    // even tile tt (buf0) -- provably non-diagonal (tt <= nt-2)
    WAITBAR;                                     // drains S(tt) only
    STAGE(8192, tt + 1);                         // -> buf1
    COMPUTE(0, false, 0);
    // odd tile tt+1 (buf1) -- diagonal iff tt+2 == nt
    WAITBAR;                                     // drains S(tt+1) only
    {
      int pj = tt + 2; if (pj >= nt) pj = 0;     // clamped prefetch (unused if wrap)
      STAGE(0, pj);                              // -> buf0
    }
    COMPUTE(8192, (tt + 2 == nt), (tt + 1));
  }
  if (tt < nt) {                                 // odd-nt tail: diagonal tile
    WAITBAR;
    COMPUTE(0, true, tt);
  }
#undef STAGE
#undef COMPUTE
#undef WAITBAR

  // --- cross-lane l-reduction, once ---
  rl += __shfl_xor(rl, 16);
  rl += __shfl_xor(rl, 32);
  const float inv = 1.0f / rl;
#pragma unroll
  for (int dt = 0; dt < 4; ++dt) {
    uint2 st;
    st.x = cvt_pk_bf16(o[dt][0] * inv, o[dt][1] * inv);
    st.y = cvt_pk_bf16(o[dt][2] * inv, o[dt][3] * inv);
    *(uint2*)(O + (tokbase + q0 + r16) * DD + hoff + dt * 16 + g * 4) = st;
  }
}

// ---------------------------------------------------------------------------
// Launch: prep (wave-LN + wtrans fused) -> fused QKV GEMM -> attn -> O-GEMM.
// ws: xn 8MB | q 8MB | k 8MB | vt 8MB | att 8MB | wt 16MB  (56MB)
// ---------------------------------------------------------------------------
extern "C" void kernel_launch(void* const* d_in, const int* in_sizes, int n_in,
                              void* d_out, int out_size, void* d_ws, size_t ws_size,
                              hipStream_t stream) {
  const float* x    = (const float*)d_in[0];
  const float* ln_g = (const float*)d_in[1];
  const float* ln_b = (const float*)d_in[2];
  const float* Wq   = (const float*)d_in[3];
  const float* bq   = (const float*)d_in[4];
  const float* Wk   = (const float*)d_in[5];
  const float* bk   = (const float*)d_in[6];
  const float* Wv   = (const float*)d_in[7];
  const float* bv   = (const float*)d_in[8];
  const float* Wo   = (const float*)d_in[9];
  const float* bo   = (const float*)d_in[10];
  float* out = (float*)d_out;

  ushort* ws  = (ushort*)d_ws;
  ushort* xn  = ws;
  ushort* qb  = xn + NE;
  ushort* kb  = qb + NE;
  ushort* vt  = kb + NE;
  ushort* ab  = vt + NE;
  ushort* wt  = ab + NE;               // 4 x [1024][1024] bf16
  ushort* wot = wt + (size_t)3 * DD * DD;

  prep<<<NROWS / 4 + 1024, 256, 0, stream>>>(x, ln_g, ln_b, xn, Wq, Wk, Wv, Wo, wt);

  gemm_qkv<<<dim3(NROWS / 128, 24), 256, 0, stream>>>(xn, wt, bq, bk, bv,
                                                      qb, kb, vt);

  attn_mfma<<<BB * HH * (SS / 64), 256, 0, stream>>>(qb, kb, vt, ab);

  gemm_o<<<dim3(NROWS / 128, DD / 64), 256, 0, stream>>>(ab, wot, bo, x, out);
}